// Round 1
// baseline (471.124 us; speedup 1.0000x reference)
//
#include <hip/hip_runtime.h>

typedef unsigned short u16;
typedef __attribute__((ext_vector_type(8))) short short8;
typedef __attribute__((ext_vector_type(4))) unsigned short ushort4v;
typedef __attribute__((ext_vector_type(4))) float float4v;

__device__ __forceinline__ float bf2f(u16 u) {
  union { unsigned int i; float f; } c; c.i = ((unsigned int)u) << 16; return c.f;
}
__device__ __forceinline__ u16 f2bf(float f) {
  union { float f; unsigned int i; } c; c.f = f;
  unsigned int u = c.i;
  return (u16)((u + 0x7fffu + ((u >> 16) & 1u)) >> 16);
}
// 0.5x(1+tanh(c(x+0.044715x^3))) == x * sigmoid(2c(x+0.044715x^3))
//   == x / (1 + exp2(-(k1*x + k3*x^3))), k1 = 2c*log2(e), k3 = k1*0.044715
__device__ __forceinline__ float gelu_new(float x) {
  const float k1 = 2.30218776f;
  const float k3 = 0.10294233f;
  float x3 = x * x * x;
  float e = __builtin_amdgcn_exp2f(-(k1 * x + k3 * x3));
  return x / (1.0f + e);
}
__device__ __forceinline__ float ldres(const float* p) { return *p; }
__device__ __forceinline__ float ldres(const u16* p) { return bf2f(*p); }

__device__ __forceinline__ void gload_lds16(const u16* g, u16* l) {
  __builtin_amdgcn_global_load_lds(
      (const __attribute__((address_space(1))) unsigned int*)g,
      (__attribute__((address_space(3))) unsigned int*)l, 16, 0, 0);
}

// ---------------- prep kernels ----------------
__global__ void cvt_bf16(const float* __restrict__ src, u16* __restrict__ dst) {
  int t = blockIdx.x * 256 + threadIdx.x;
  float4v a = *(const float4v*)(src + (size_t)t * 8);
  float4v b = *(const float4v*)(src + (size_t)t * 8 + 4);
  short8 o;
#pragma unroll
  for (int j = 0; j < 4; ++j) o[j] = (short)f2bf(a[j]);
#pragma unroll
  for (int j = 0; j < 4; ++j) o[4 + j] = (short)f2bf(b[j]);
  *(short8*)(dst + (size_t)t * 8) = o;
}

// W_O [16,1024,64] f32 -> Wot[d, i*64+h] bf16
__global__ void prep_wo(const float* __restrict__ WO, u16* __restrict__ Wot) {
  int t = blockIdx.x * 256 + threadIdx.x;  // 0..131071
  int i = t >> 13;
  int d = (t >> 3) & 1023;
  int h0 = (t & 7) * 8;
  const float* src = WO + (size_t)i * 65536 + d * 64 + h0;
  float4v a = *(const float4v*)(src);
  float4v b = *(const float4v*)(src + 4);
  short8 o;
#pragma unroll
  for (int j = 0; j < 4; ++j) o[j] = (short)f2bf(a[j]);
#pragma unroll
  for (int j = 0; j < 4; ++j) o[4 + j] = (short)f2bf(b[j]);
  *(short8*)(Wot + (size_t)d * 1024 + i * 64 + h0) = o;
}

__global__ void prep_bqkv(const float* __restrict__ bQ, const float* __restrict__ bK,
                          const float* __restrict__ bV, float* __restrict__ bqkv) {
  int t = blockIdx.x * 256 + threadIdx.x;
  if (t < 3072)
    bqkv[t] = (t < 1024) ? bQ[t] : (t < 2048) ? bK[t - 1024] : bV[t - 2048];
}

// ---------------- layernorm (ln_pre): f32 in -> bf16 out ----------------
__global__ void ln_f32(const float* __restrict__ x, u16* __restrict__ y) {
  __shared__ float red1[4];
  __shared__ float red2[4];
  int token = blockIdx.x;
  int tid = threadIdx.x;
  int w = tid >> 6;
  const float* xr = x + (size_t)token * 1024;
  float4v v = *(const float4v*)(xr + tid * 4);
  float s = v[0] + v[1] + v[2] + v[3];
#pragma unroll
  for (int m = 32; m >= 1; m >>= 1) s += __shfl_xor(s, m);
  if ((tid & 63) == 0) red1[w] = s;
  __syncthreads();
  float mean = (red1[0] + red1[1] + red1[2] + red1[3]) * (1.0f / 1024.0f);
  float ss = 0.0f;
#pragma unroll
  for (int j = 0; j < 4; ++j) { v[j] -= mean; ss += v[j] * v[j]; }
#pragma unroll
  for (int m = 32; m >= 1; m >>= 1) ss += __shfl_xor(ss, m);
  if ((tid & 63) == 0) red2[w] = ss;
  __syncthreads();
  float ms = (red2[0] + red2[1] + red2[2] + red2[3]) * (1.0f / 1024.0f);
  float inv = 1.0f / sqrtf(ms + 1e-5f);
  ushort4v o;
#pragma unroll
  for (int j = 0; j < 4; ++j) o[j] = f2bf(v[j] * inv);
  *(ushort4v*)(y + (size_t)token * 1024 + tid * 4) = o;
}

// ---------------- GEMM: C[M,N] = A[M,K](bf16, stride lda) * Bw[N,K]^T ----------------
// VSPLIT: cols >= 2048 are written transposed to vTout[(col-2048)*4096 + row].
// ATOMIC: split-K over blockIdx.z; each block covers kPer of K and atomically
//         accumulates f32 partials into C (which must be pre-zeroed).
//         bias+resid are folded in by the blockIdx.z==0 blocks only.
template <int BN, int BK, bool GELU, bool VSPLIT, bool ATOMIC, typename TO, typename TR>
__global__ __launch_bounds__(256) void gemm_bt(
    const u16* __restrict__ A, const u16* __restrict__ Bw,
    const float* __restrict__ bias, const TR* __restrict__ resid,
    TO* __restrict__ C, u16* __restrict__ vTout, int M, int N, int K,
    int lda, int ldc, int kPer) {
  constexpr int BM = 128;
  constexpr int SEGS = BK / 8;           // 16B chunks per tile row
  constexpr int FI = 4, FJ = BN / 32;
  constexpr int CA = BM * SEGS / 256;    // chunks per thread (A tile)
  constexpr int CB = BN * SEGS / 256;
  __shared__ __align__(16) u16 As[BM * BK];
  __shared__ __align__(16) u16 Bs[BN * BK];
  const int tid = threadIdx.x;
  const int w = tid >> 6, lane = tid & 63;
  const int quad = lane >> 4, l16 = lane & 15;
  const int m0 = blockIdx.x * BM, n0 = blockIdx.y * BN;
  const int wm = (w >> 1) * 64, wn = (w & 1) * (BN / 2);
  const int kBase = ATOMIC ? blockIdx.z * kPer : 0;
  float4v acc[FI][FJ] = {};
  for (int k0 = kBase; k0 < kBase + kPer; k0 += BK) {
    __syncthreads();
#pragma unroll
    for (int t = 0; t < CA; ++t) {
      int chunk = (w * CA + t) * 64 + lane;
      int row = chunk / SEGS, seg = chunk % SEGS;
      gload_lds16(A + (size_t)(m0 + row) * lda + k0 + seg * 8,
                  As + (w * CA + t) * 512);
    }
#pragma unroll
    for (int t = 0; t < CB; ++t) {
      int chunk = (w * CB + t) * 64 + lane;
      int row = chunk / SEGS, seg = chunk % SEGS;
      gload_lds16(Bw + (size_t)(n0 + row) * K + k0 + seg * 8,
                  Bs + (w * CB + t) * 512);
    }
    __syncthreads();
#pragma unroll
    for (int kk = 0; kk < BK; kk += 32) {
      short8 a[FI], b[FJ];
#pragma unroll
      for (int fi = 0; fi < FI; ++fi)
        a[fi] = *(const short8*)(As + (wm + fi * 16 + l16) * BK + kk + quad * 8);
#pragma unroll
      for (int fj = 0; fj < FJ; ++fj)
        b[fj] = *(const short8*)(Bs + (wn + fj * 16 + l16) * BK + kk + quad * 8);
#pragma unroll
      for (int fi = 0; fi < FI; ++fi)
#pragma unroll
        for (int fj = 0; fj < FJ; ++fj)
          acc[fi][fj] = __builtin_amdgcn_mfma_f32_16x16x32_bf16(
              a[fi], b[fj], acc[fi][fj], 0, 0, 0);
    }
  }
  const bool lead = !ATOMIC || blockIdx.z == 0;
#pragma unroll
  for (int fi = 0; fi < FI; ++fi) {
#pragma unroll
    for (int fj = 0; fj < FJ; ++fj) {
      int col = n0 + wn + fj * 16 + l16;
      float bv = (bias && lead) ? bias[col] : 0.0f;
#pragma unroll
      for (int r = 0; r < 4; ++r) {
        int row = m0 + wm + fi * 16 + quad * 4 + r;
        float val = acc[fi][fj][r] + bv;
        if (resid && lead) val += ldres(resid + (size_t)row * N + col);
        if (GELU) val = gelu_new(val);
        if constexpr (ATOMIC) {
          unsafeAtomicAdd((float*)(C + (size_t)row * ldc + col), val);
        } else if (VSPLIT && col >= 2048) {
          vTout[(size_t)(col - 2048) * 4096 + row] = f2bf(val);
        } else if constexpr (sizeof(TO) == 2) {
          C[(size_t)row * ldc + col] = f2bf(val);
        } else {
          C[(size_t)row * ldc + col] = val;
        }
      }
    }
  }
}

// ---------------- single-pass flash attention (causal, online softmax, exp2) ----------------
// qk: [B*S, 2048] (q|k); vT: [1024][4096] = V transposed. z -> q half of qk.
// Grid: 1024 linear blocks; id = qtile_rev*32 + (head*2+b) so that id%8 groups
// all q-tiles of one (b,h) on one XCD (K/V stays in that XCD's 4MB L2).
__global__ __launch_bounds__(256) void attn_flash(u16* __restrict__ qk,
                                                  const u16* __restrict__ vT) {
  constexpr int PADK = 72;
  constexpr float C2 = 0.18033688011112042f;  // (1/8) * log2(e)
  __shared__ __align__(16) u16 Ks[64 * PADK];
  __shared__ __align__(16) u16 Vt[64 * PADK];
  __shared__ __align__(16) u16 Ps[4][16 * PADK];
  const int id = blockIdx.x;
  const int qt = 31 - (id >> 5);  // longest blocks first
  const int combo = id & 31;
  const int head = combo >> 1, b = combo & 1;
  const int tid = threadIdx.x;
  const int w = tid >> 6, lane = tid & 63;
  const int quad = lane >> 4, l16 = lane & 15;
  const int q0 = qt * 64;
  const size_t tokB = (size_t)b * 2048;

  short8 aq[2];
#pragma unroll
  for (int ks = 0; ks < 2; ++ks)
    aq[ks] = *(const short8*)(qk + (tokB + q0 + w * 16 + l16) * 2048 +
                              head * 64 + ks * 32 + quad * 8);

  const u16* kbase = qk + tokB * 2048 + 1024 + head * 64;   // + (kk0+row)*2048 + seg*8
  const u16* vbase = vT + (size_t)head * 64 * 4096 + tokB;  // + row*4096 + kk0 + seg*8

  float m_st[4] = {-1e30f, -1e30f, -1e30f, -1e30f};
  float l_st[4] = {0.f, 0.f, 0.f, 0.f};
  float4v o_acc[4] = {};

  for (int kt = 0; kt <= qt; ++kt) {
    const int kk0 = kt * 64;
    __syncthreads();
#pragma unroll
    for (int i = 0; i < 2; ++i) {
      int flat = tid * 2 + i;  // 0..511
      int row = flat >> 3, seg = flat & 7;
      *(short8*)(Ks + row * PADK + seg * 8) =
          *(const short8*)(kbase + (size_t)(kk0 + row) * 2048 + seg * 8);
      *(short8*)(Vt + row * PADK + seg * 8) =
          *(const short8*)(vbase + (size_t)row * 4096 + kk0 + seg * 8);
    }
    __syncthreads();

    float4v s[4];
#pragma unroll
    for (int fj = 0; fj < 4; ++fj) {
      float4v t = {0.f, 0.f, 0.f, 0.f};
#pragma unroll
      for (int ks = 0; ks < 2; ++ks) {
        short8 bk = *(const short8*)(Ks + (fj * 16 + l16) * PADK + ks * 32 + quad * 8);
        t = __builtin_amdgcn_mfma_f32_16x16x32_bf16(aq[ks], bk, t, 0, 0, 0);
      }
      s[fj] = t;
    }
#pragma unroll
    for (int fj = 0; fj < 4; ++fj)
#pragma unroll
      for (int r = 0; r < 4; ++r) s[fj][r] *= C2;
    if (kt == qt) {
#pragma unroll
      for (int fj = 0; fj < 4; ++fj) {
        int col = kk0 + fj * 16 + l16;
#pragma unroll
        for (int r = 0; r < 4; ++r) {
          int row = q0 + w * 16 + quad * 4 + r;
          if (col > row) s[fj][r] = -1e30f;
        }
      }
    }
    float mx[4];
#pragma unroll
    for (int r = 0; r < 4; ++r) {
      float m = s[0][r];
#pragma unroll
      for (int fj = 1; fj < 4; ++fj) m = fmaxf(m, s[fj][r]);
      m = fmaxf(m, __shfl_xor(m, 1));
      m = fmaxf(m, __shfl_xor(m, 2));
      m = fmaxf(m, __shfl_xor(m, 4));
      m = fmaxf(m, __shfl_xor(m, 8));
      mx[r] = m;
    }
    float alpha[4];
#pragma unroll
    for (int r = 0; r < 4; ++r) {
      float mnew = fmaxf(m_st[r], mx[r]);
      alpha[r] = __builtin_amdgcn_exp2f(m_st[r] - mnew);
      m_st[r] = mnew;
    }
    float rs[4] = {0.f, 0.f, 0.f, 0.f};
#pragma unroll
    for (int fj = 0; fj < 4; ++fj)
#pragma unroll
      for (int r = 0; r < 4; ++r) {
        float pv = __builtin_amdgcn_exp2f(s[fj][r] - m_st[r]);
        s[fj][r] = pv;
        rs[r] += pv;
      }
#pragma unroll
    for (int r = 0; r < 4; ++r) {
      float t = rs[r];
      t += __shfl_xor(t, 1);
      t += __shfl_xor(t, 2);
      t += __shfl_xor(t, 4);
      t += __shfl_xor(t, 8);
      l_st[r] = l_st[r] * alpha[r] + t;
    }
#pragma unroll
    for (int fj = 0; fj < 4; ++fj)
#pragma unroll
      for (int r = 0; r < 4; ++r) o_acc[fj][r] *= alpha[r];
#pragma unroll
    for (int fj = 0; fj < 4; ++fj)
#pragma unroll
      for (int r = 0; r < 4; ++r)
        Ps[w][(quad * 4 + r) * PADK + fj * 16 + l16] = f2bf(s[fj][r]);
    short8 ap[2];
#pragma unroll
    for (int ks = 0; ks < 2; ++ks)
      ap[ks] = *(const short8*)(&Ps[w][l16 * PADK + ks * 32 + quad * 8]);
#pragma unroll
    for (int fj = 0; fj < 4; ++fj)
#pragma unroll
      for (int ks = 0; ks < 2; ++ks) {
        short8 bv = *(const short8*)(Vt + (fj * 16 + l16) * PADK + ks * 32 + quad * 8);
        o_acc[fj] = __builtin_amdgcn_mfma_f32_16x16x32_bf16(ap[ks], bv, o_acc[fj], 0, 0, 0);
      }
  }
#pragma unroll
  for (int r = 0; r < 4; ++r) {
    float inv = 1.0f / l_st[r];
    int row = q0 + w * 16 + quad * 4 + r;
#pragma unroll
    for (int fj = 0; fj < 4; ++fj)
      qk[(tokB + row) * 2048 + head * 64 + fj * 16 + l16] =
          f2bf(o_acc[fj][r] * inv);
  }
}

// ---------------- launcher ----------------
extern "C" void kernel_launch(void* const* d_in, const int* in_sizes, int n_in,
                              void* d_out, int out_size, void* d_ws, size_t ws_size,
                              hipStream_t stream) {
  const float* x = (const float*)d_in[0];
  const float* W_Q = (const float*)d_in[1];
  const float* W_K = (const float*)d_in[2];
  const float* W_V = (const float*)d_in[3];
  const float* W_O = (const float*)d_in[4];
  const float* b_Q = (const float*)d_in[5];
  const float* b_K = (const float*)d_in[6];
  const float* b_V = (const float*)d_in[7];
  const float* b_O = (const float*)d_in[8];
  const float* W_in = (const float*)d_in[9];
  const float* b_in = (const float*)d_in[10];
  const float* W_out = (const float*)d_in[11];
  const float* b_out = (const float*)d_in[12];
  float* out = (float*)d_out;

  char* ws = (char*)d_ws;
  u16* Wqkv = (u16*)(ws);                 // [0, 6291456)
  u16* Wot  = (u16*)(ws + 6291456);       // [6291456, 8388608)
  u16* Wib  = (u16*)(ws + 8388608);       // [8388608, 16777216)
  u16* Wob  = (u16*)(ws + 16777216);      // [16777216, 25165824)
  float* bqkv = (float*)(ws + 25165824);  // [25165824, 25178112)
  u16* xn   = (u16*)(ws + 25178112);      // [25178112, 33566720)
  u16* qk   = (u16*)(ws + 33566720);      // [33566720, 50343936)  4096*2048 bf16
  u16* vT   = (u16*)(ws + 50343936);      // [50343936, 58732544)  1024*4096 bf16
  u16* hbuf = (u16*)(ws + 33566720);      // overlays qk+vT, 4096*4096, ends 67121152
  float* rm = (float*)(ws + 67121152);    // [67121152, 83898368)

  // zero the split-K atomic accumulation targets (stream-ordered, capture-safe)
  hipMemsetAsync(rm, 0, (size_t)4096 * 1024 * 4, stream);
  hipMemsetAsync(out, 0, (size_t)4096 * 1024 * 4, stream);

  cvt_bf16<<<512, 256, 0, stream>>>(W_Q, Wqkv);
  cvt_bf16<<<512, 256, 0, stream>>>(W_K, Wqkv + 1048576);
  cvt_bf16<<<512, 256, 0, stream>>>(W_V, Wqkv + 2097152);
  cvt_bf16<<<2048, 256, 0, stream>>>(W_in, Wib);
  cvt_bf16<<<2048, 256, 0, stream>>>(W_out, Wob);
  prep_wo<<<512, 256, 0, stream>>>(W_O, Wot);
  prep_bqkv<<<12, 256, 0, stream>>>(b_Q, b_K, b_V, bqkv);

  ln_f32<<<4096, 256, 0, stream>>>(x, xn);
  // QKV: Q,K -> qk[4096][2048]; V -> vT[1024][4096] (transposed in epilogue)
  gemm_bt<128, 32, false, true, false, u16, float><<<dim3(32, 24), 256, 0, stream>>>(
      xn, Wqkv, bqkv, (const float*)nullptr, qk, vT, 4096, 3072, 1024, 1024, 2048, 1024);
  attn_flash<<<1024, 256, 0, stream>>>(qk, vT);
  // attn-out: 128x128 tiles, split-K=2, atomic accumulate into zeroed rm.
  // z==0 blocks fold in resid (x) + b_O.
  gemm_bt<128, 32, false, false, true, float, float><<<dim3(32, 8, 2), 256, 0, stream>>>(
      qk /*z in q half, lda=2048*/, Wot, b_O, x, rm, nullptr, 4096, 1024, 1024, 2048, 1024, 512);
  ln_f32<<<4096, 256, 0, stream>>>(rm, xn);
  gemm_bt<128, 32, true, false, false, u16, float><<<dim3(32, 32), 256, 0, stream>>>(
      xn, Wib, b_in, (const float*)nullptr, hbuf, nullptr, 4096, 4096, 1024, 1024, 4096, 1024);
  // MLP-out: 128x128 tiles, split-K=4, atomic accumulate into zeroed out.
  // z==0 blocks fold in resid (rm) + b_out.
  gemm_bt<128, 32, false, false, true, float, float><<<dim3(32, 8, 4), 256, 0, stream>>>(
      hbuf, Wob, b_out, rm, out, nullptr, 4096, 1024, 4096, 4096, 1024, 1024);
}

// Round 2
// 420.234 us; speedup vs baseline: 1.1211x; 1.1211x over previous
//
#include <hip/hip_runtime.h>

typedef unsigned short u16;
typedef __attribute__((ext_vector_type(8))) short short8;
typedef __attribute__((ext_vector_type(4))) unsigned short ushort4v;
typedef __attribute__((ext_vector_type(4))) float float4v;

__device__ __forceinline__ float bf2f(u16 u) {
  union { unsigned int i; float f; } c; c.i = ((unsigned int)u) << 16; return c.f;
}
__device__ __forceinline__ u16 f2bf(float f) {
  union { float f; unsigned int i; } c; c.f = f;
  unsigned int u = c.i;
  return (u16)((u + 0x7fffu + ((u >> 16) & 1u)) >> 16);
}
// 0.5x(1+tanh(c(x+0.044715x^3))) == x * sigmoid(2c(x+0.044715x^3))
//   == x / (1 + exp2(-(k1*x + k3*x^3))), k1 = 2c*log2(e), k3 = k1*0.044715
__device__ __forceinline__ float gelu_new(float x) {
  const float k1 = 2.30218776f;
  const float k3 = 0.10294233f;
  float x3 = x * x * x;
  float e = __builtin_amdgcn_exp2f(-(k1 * x + k3 * x3));
  return x / (1.0f + e);
}
__device__ __forceinline__ float ldres(const float* p) { return *p; }
__device__ __forceinline__ float ldres(const u16* p) { return bf2f(*p); }

__device__ __forceinline__ void gload_lds16(const u16* g, u16* l) {
  __builtin_amdgcn_global_load_lds(
      (const __attribute__((address_space(1))) unsigned int*)g,
      (__attribute__((address_space(3))) unsigned int*)l, 16, 0, 0);
}

// ---------------- prep kernels ----------------
__global__ void cvt_bf16(const float* __restrict__ src, u16* __restrict__ dst) {
  int t = blockIdx.x * 256 + threadIdx.x;
  float4v a = *(const float4v*)(src + (size_t)t * 8);
  float4v b = *(const float4v*)(src + (size_t)t * 8 + 4);
  short8 o;
#pragma unroll
  for (int j = 0; j < 4; ++j) o[j] = (short)f2bf(a[j]);
#pragma unroll
  for (int j = 0; j < 4; ++j) o[4 + j] = (short)f2bf(b[j]);
  *(short8*)(dst + (size_t)t * 8) = o;
}

// W_O [16,1024,64] f32 -> Wot[d, i*64+h] bf16
__global__ void prep_wo(const float* __restrict__ WO, u16* __restrict__ Wot) {
  int t = blockIdx.x * 256 + threadIdx.x;  // 0..131071
  int i = t >> 13;
  int d = (t >> 3) & 1023;
  int h0 = (t & 7) * 8;
  const float* src = WO + (size_t)i * 65536 + d * 64 + h0;
  float4v a = *(const float4v*)(src);
  float4v b = *(const float4v*)(src + 4);
  short8 o;
#pragma unroll
  for (int j = 0; j < 4; ++j) o[j] = (short)f2bf(a[j]);
#pragma unroll
  for (int j = 0; j < 4; ++j) o[4 + j] = (short)f2bf(b[j]);
  *(short8*)(Wot + (size_t)d * 1024 + i * 64 + h0) = o;
}

__global__ void prep_bqkv(const float* __restrict__ bQ, const float* __restrict__ bK,
                          const float* __restrict__ bV, float* __restrict__ bqkv) {
  int t = blockIdx.x * 256 + threadIdx.x;
  if (t < 3072)
    bqkv[t] = (t < 1024) ? bQ[t] : (t < 2048) ? bK[t - 1024] : bV[t - 2048];
}

// ---------------- layernorm (ln_pre): f32 in -> bf16 out ----------------
__global__ void ln_f32(const float* __restrict__ x, u16* __restrict__ y) {
  __shared__ float red1[4];
  __shared__ float red2[4];
  int token = blockIdx.x;
  int tid = threadIdx.x;
  int w = tid >> 6;
  const float* xr = x + (size_t)token * 1024;
  float4v v = *(const float4v*)(xr + tid * 4);
  float s = v[0] + v[1] + v[2] + v[3];
#pragma unroll
  for (int m = 32; m >= 1; m >>= 1) s += __shfl_xor(s, m);
  if ((tid & 63) == 0) red1[w] = s;
  __syncthreads();
  float mean = (red1[0] + red1[1] + red1[2] + red1[3]) * (1.0f / 1024.0f);
  float ss = 0.0f;
#pragma unroll
  for (int j = 0; j < 4; ++j) { v[j] -= mean; ss += v[j] * v[j]; }
#pragma unroll
  for (int m = 32; m >= 1; m >>= 1) ss += __shfl_xor(ss, m);
  if ((tid & 63) == 0) red2[w] = ss;
  __syncthreads();
  float ms = (red2[0] + red2[1] + red2[2] + red2[3]) * (1.0f / 1024.0f);
  float inv = 1.0f / sqrtf(ms + 1e-5f);
  ushort4v o;
#pragma unroll
  for (int j = 0; j < 4; ++j) o[j] = f2bf(v[j] * inv);
  *(ushort4v*)(y + (size_t)token * 1024 + tid * 4) = o;
}

// ---------------- split-K reduce: out = out(P0+bias) + P1 + P2 + P3 + rm ----------------
__global__ void reduce_mlp(float* __restrict__ out, const u16* __restrict__ p1,
                           const u16* __restrict__ p2, const u16* __restrict__ p3,
                           const float* __restrict__ rm) {
  size_t t = (size_t)blockIdx.x * 256 + threadIdx.x;  // handles 8 f32 elems
  float4v o0 = *(float4v*)(out + t * 8);
  float4v o1 = *(float4v*)(out + t * 8 + 4);
  short8 a = *(const short8*)(p1 + t * 8);
  short8 b = *(const short8*)(p2 + t * 8);
  short8 c = *(const short8*)(p3 + t * 8);
  float4v r0 = *(const float4v*)(rm + t * 8);
  float4v r1 = *(const float4v*)(rm + t * 8 + 4);
#pragma unroll
  for (int j = 0; j < 4; ++j)
    o0[j] += bf2f((u16)a[j]) + bf2f((u16)b[j]) + bf2f((u16)c[j]) + r0[j];
#pragma unroll
  for (int j = 0; j < 4; ++j)
    o1[j] += bf2f((u16)a[4 + j]) + bf2f((u16)b[4 + j]) + bf2f((u16)c[4 + j]) + r1[j];
  *(float4v*)(out + t * 8) = o0;
  *(float4v*)(out + t * 8 + 4) = o1;
}

// ---------------- GEMM: C[M,N] = A[M,K](bf16, stride lda) * Bw[N,K]^T ----------------
// VSPLIT: cols >= 2048 are written transposed to vTout[(col-2048)*4096 + row].
// SPLITK: split-K over blockIdx.z (kPer of K each). z==0 writes f32 (acc+bias)
//         to C; z==1..3 write bf16 partials to p1(=vTout slot)/p2/p3.
//         resid is folded in by the separate reduce kernel.
template <int BN, int BK, bool GELU, bool VSPLIT, bool SPLITK, typename TO, typename TR>
__global__ __launch_bounds__(256) void gemm_bt(
    const u16* __restrict__ A, const u16* __restrict__ Bw,
    const float* __restrict__ bias, const TR* __restrict__ resid,
    TO* __restrict__ C, u16* __restrict__ vTout, u16* __restrict__ p2,
    u16* __restrict__ p3, int M, int N, int K, int lda, int ldc, int kPer) {
  constexpr int BM = 128;
  constexpr int SEGS = BK / 8;           // 16B chunks per tile row
  constexpr int FI = 4, FJ = BN / 32;
  constexpr int CA = BM * SEGS / 256;    // chunks per thread (A tile)
  constexpr int CB = BN * SEGS / 256;
  __shared__ __align__(16) u16 As[BM * BK];
  __shared__ __align__(16) u16 Bs[BN * BK];
  const int tid = threadIdx.x;
  const int w = tid >> 6, lane = tid & 63;
  const int quad = lane >> 4, l16 = lane & 15;
  const int m0 = blockIdx.x * BM, n0 = blockIdx.y * BN;
  const int wm = (w >> 1) * 64, wn = (w & 1) * (BN / 2);
  const int kBase = SPLITK ? blockIdx.z * kPer : 0;
  float4v acc[FI][FJ] = {};
  for (int k0 = kBase; k0 < kBase + kPer; k0 += BK) {
    __syncthreads();
#pragma unroll
    for (int t = 0; t < CA; ++t) {
      int chunk = (w * CA + t) * 64 + lane;
      int row = chunk / SEGS, seg = chunk % SEGS;
      gload_lds16(A + (size_t)(m0 + row) * lda + k0 + seg * 8,
                  As + (w * CA + t) * 512);
    }
#pragma unroll
    for (int t = 0; t < CB; ++t) {
      int chunk = (w * CB + t) * 64 + lane;
      int row = chunk / SEGS, seg = chunk % SEGS;
      gload_lds16(Bw + (size_t)(n0 + row) * K + k0 + seg * 8,
                  Bs + (w * CB + t) * 512);
    }
    __syncthreads();
#pragma unroll
    for (int kk = 0; kk < BK; kk += 32) {
      short8 a[FI], b[FJ];
#pragma unroll
      for (int fi = 0; fi < FI; ++fi)
        a[fi] = *(const short8*)(As + (wm + fi * 16 + l16) * BK + kk + quad * 8);
#pragma unroll
      for (int fj = 0; fj < FJ; ++fj)
        b[fj] = *(const short8*)(Bs + (wn + fj * 16 + l16) * BK + kk + quad * 8);
#pragma unroll
      for (int fi = 0; fi < FI; ++fi)
#pragma unroll
        for (int fj = 0; fj < FJ; ++fj)
          acc[fi][fj] = __builtin_amdgcn_mfma_f32_16x16x32_bf16(
              a[fi], b[fj], acc[fi][fj], 0, 0, 0);
    }
  }
  const bool lead = !SPLITK || blockIdx.z == 0;
#pragma unroll
  for (int fi = 0; fi < FI; ++fi) {
#pragma unroll
    for (int fj = 0; fj < FJ; ++fj) {
      int col = n0 + wn + fj * 16 + l16;
      float bv = (bias && lead) ? bias[col] : 0.0f;
#pragma unroll
      for (int r = 0; r < 4; ++r) {
        int row = m0 + wm + fi * 16 + quad * 4 + r;
        float val = acc[fi][fj][r] + bv;
        if (resid && lead) val += ldres(resid + (size_t)row * N + col);
        if (GELU) val = gelu_new(val);
        if constexpr (SPLITK) {
          if (blockIdx.z == 0) {
            C[(size_t)row * ldc + col] = val;  // f32, bias folded
          } else {
            u16* pz = (blockIdx.z == 1) ? vTout : (blockIdx.z == 2) ? p2 : p3;
            pz[(size_t)row * ldc + col] = f2bf(val);
          }
        } else if (VSPLIT && col >= 2048) {
          vTout[(size_t)(col - 2048) * 4096 + row] = f2bf(val);
        } else if constexpr (sizeof(TO) == 2) {
          C[(size_t)row * ldc + col] = f2bf(val);
        } else {
          C[(size_t)row * ldc + col] = val;
        }
      }
    }
  }
}

// ---------------- single-pass flash attention (causal, online softmax, exp2) ----------------
// qk: [B*S, 2048] (q|k); vT: [1024][4096] = V transposed. z -> q half of qk.
// Grid: 1024 linear blocks; id = qtile_rev*32 + (head*2+b) so that id%8 groups
// all q-tiles of one (b,h) on one XCD (K/V stays in that XCD's 4MB L2).
__global__ __launch_bounds__(256) void attn_flash(u16* __restrict__ qk,
                                                  const u16* __restrict__ vT) {
  constexpr int PADK = 72;
  constexpr float C2 = 0.18033688011112042f;  // (1/8) * log2(e)
  __shared__ __align__(16) u16 Ks[64 * PADK];
  __shared__ __align__(16) u16 Vt[64 * PADK];
  __shared__ __align__(16) u16 Ps[4][16 * PADK];
  const int id = blockIdx.x;
  const int qt = 31 - (id >> 5);  // longest blocks first
  const int combo = id & 31;
  const int head = combo >> 1, b = combo & 1;
  const int tid = threadIdx.x;
  const int w = tid >> 6, lane = tid & 63;
  const int quad = lane >> 4, l16 = lane & 15;
  const int q0 = qt * 64;
  const size_t tokB = (size_t)b * 2048;

  short8 aq[2];
#pragma unroll
  for (int ks = 0; ks < 2; ++ks)
    aq[ks] = *(const short8*)(qk + (tokB + q0 + w * 16 + l16) * 2048 +
                              head * 64 + ks * 32 + quad * 8);

  const u16* kbase = qk + tokB * 2048 + 1024 + head * 64;   // + (kk0+row)*2048 + seg*8
  const u16* vbase = vT + (size_t)head * 64 * 4096 + tokB;  // + row*4096 + kk0 + seg*8

  float m_st[4] = {-1e30f, -1e30f, -1e30f, -1e30f};
  float l_st[4] = {0.f, 0.f, 0.f, 0.f};
  float4v o_acc[4] = {};

  for (int kt = 0; kt <= qt; ++kt) {
    const int kk0 = kt * 64;
    __syncthreads();
#pragma unroll
    for (int i = 0; i < 2; ++i) {
      int flat = tid * 2 + i;  // 0..511
      int row = flat >> 3, seg = flat & 7;
      *(short8*)(Ks + row * PADK + seg * 8) =
          *(const short8*)(kbase + (size_t)(kk0 + row) * 2048 + seg * 8);
      *(short8*)(Vt + row * PADK + seg * 8) =
          *(const short8*)(vbase + (size_t)row * 4096 + kk0 + seg * 8);
    }
    __syncthreads();

    float4v s[4];
#pragma unroll
    for (int fj = 0; fj < 4; ++fj) {
      float4v t = {0.f, 0.f, 0.f, 0.f};
#pragma unroll
      for (int ks = 0; ks < 2; ++ks) {
        short8 bk = *(const short8*)(Ks + (fj * 16 + l16) * PADK + ks * 32 + quad * 8);
        t = __builtin_amdgcn_mfma_f32_16x16x32_bf16(aq[ks], bk, t, 0, 0, 0);
      }
      s[fj] = t;
    }
#pragma unroll
    for (int fj = 0; fj < 4; ++fj)
#pragma unroll
      for (int r = 0; r < 4; ++r) s[fj][r] *= C2;
    if (kt == qt) {
#pragma unroll
      for (int fj = 0; fj < 4; ++fj) {
        int col = kk0 + fj * 16 + l16;
#pragma unroll
        for (int r = 0; r < 4; ++r) {
          int row = q0 + w * 16 + quad * 4 + r;
          if (col > row) s[fj][r] = -1e30f;
        }
      }
    }
    float mx[4];
#pragma unroll
    for (int r = 0; r < 4; ++r) {
      float m = s[0][r];
#pragma unroll
      for (int fj = 1; fj < 4; ++fj) m = fmaxf(m, s[fj][r]);
      m = fmaxf(m, __shfl_xor(m, 1));
      m = fmaxf(m, __shfl_xor(m, 2));
      m = fmaxf(m, __shfl_xor(m, 4));
      m = fmaxf(m, __shfl_xor(m, 8));
      mx[r] = m;
    }
    float alpha[4];
#pragma unroll
    for (int r = 0; r < 4; ++r) {
      float mnew = fmaxf(m_st[r], mx[r]);
      alpha[r] = __builtin_amdgcn_exp2f(m_st[r] - mnew);
      m_st[r] = mnew;
    }
    float rs[4] = {0.f, 0.f, 0.f, 0.f};
#pragma unroll
    for (int fj = 0; fj < 4; ++fj)
#pragma unroll
      for (int r = 0; r < 4; ++r) {
        float pv = __builtin_amdgcn_exp2f(s[fj][r] - m_st[r]);
        s[fj][r] = pv;
        rs[r] += pv;
      }
#pragma unroll
    for (int r = 0; r < 4; ++r) {
      float t = rs[r];
      t += __shfl_xor(t, 1);
      t += __shfl_xor(t, 2);
      t += __shfl_xor(t, 4);
      t += __shfl_xor(t, 8);
      l_st[r] = l_st[r] * alpha[r] + t;
    }
#pragma unroll
    for (int fj = 0; fj < 4; ++fj)
#pragma unroll
      for (int r = 0; r < 4; ++r) o_acc[fj][r] *= alpha[r];
#pragma unroll
    for (int fj = 0; fj < 4; ++fj)
#pragma unroll
      for (int r = 0; r < 4; ++r)
        Ps[w][(quad * 4 + r) * PADK + fj * 16 + l16] = f2bf(s[fj][r]);
    short8 ap[2];
#pragma unroll
    for (int ks = 0; ks < 2; ++ks)
      ap[ks] = *(const short8*)(&Ps[w][l16 * PADK + ks * 32 + quad * 8]);
#pragma unroll
    for (int fj = 0; fj < 4; ++fj)
#pragma unroll
      for (int ks = 0; ks < 2; ++ks) {
        short8 bv = *(const short8*)(Vt + (fj * 16 + l16) * PADK + ks * 32 + quad * 8);
        o_acc[fj] = __builtin_amdgcn_mfma_f32_16x16x32_bf16(ap[ks], bv, o_acc[fj], 0, 0, 0);
      }
  }
#pragma unroll
  for (int r = 0; r < 4; ++r) {
    float inv = 1.0f / l_st[r];
    int row = q0 + w * 16 + quad * 4 + r;
#pragma unroll
    for (int fj = 0; fj < 4; ++fj)
      qk[(tokB + row) * 2048 + head * 64 + fj * 16 + l16] =
          f2bf(o_acc[fj][r] * inv);
  }
}

// ---------------- launcher ----------------
extern "C" void kernel_launch(void* const* d_in, const int* in_sizes, int n_in,
                              void* d_out, int out_size, void* d_ws, size_t ws_size,
                              hipStream_t stream) {
  const float* x = (const float*)d_in[0];
  const float* W_Q = (const float*)d_in[1];
  const float* W_K = (const float*)d_in[2];
  const float* W_V = (const float*)d_in[3];
  const float* W_O = (const float*)d_in[4];
  const float* b_Q = (const float*)d_in[5];
  const float* b_K = (const float*)d_in[6];
  const float* b_V = (const float*)d_in[7];
  const float* b_O = (const float*)d_in[8];
  const float* W_in = (const float*)d_in[9];
  const float* b_in = (const float*)d_in[10];
  const float* W_out = (const float*)d_in[11];
  const float* b_out = (const float*)d_in[12];
  float* out = (float*)d_out;

  char* ws = (char*)d_ws;
  u16* Wqkv = (u16*)(ws);                 // [0, 6291456)
  u16* Wot  = (u16*)(ws + 6291456);       // [6291456, 8388608)
  u16* Wib  = (u16*)(ws + 8388608);       // [8388608, 16777216)
  u16* Wob  = (u16*)(ws + 16777216);      // [16777216, 25165824)
  float* bqkv = (float*)(ws + 25165824);  // [25165824, 25178112)
  u16* xn   = (u16*)(ws + 25178112);      // [25178112, 33566720)
  u16* qk   = (u16*)(ws + 33566720);      // [33566720, 50343936)  4096*2048 bf16
  u16* vT   = (u16*)(ws + 50343936);      // [50343936, 58732544)  1024*4096 bf16
  u16* hbuf = (u16*)(ws + 33566720);      // overlays qk+vT, 4096*4096, ends 67121152
  float* rm = (float*)(ws + 67121152);    // [67121152, 83898368)
  // split-K bf16 partials for MLP-out (regions dead by that point):
  u16* P1 = (u16*)(ws);                   // overlays Wqkv+Wot (dead after attn-out)
  u16* P2 = (u16*)(ws + 8388608);         // overlays Wib (dead after MLP-in)
  u16* P3 = (u16*)(ws + 25178112);        // overlays xn (dead after MLP-in)

  cvt_bf16<<<512, 256, 0, stream>>>(W_Q, Wqkv);
  cvt_bf16<<<512, 256, 0, stream>>>(W_K, Wqkv + 1048576);
  cvt_bf16<<<512, 256, 0, stream>>>(W_V, Wqkv + 2097152);
  cvt_bf16<<<2048, 256, 0, stream>>>(W_in, Wib);
  cvt_bf16<<<2048, 256, 0, stream>>>(W_out, Wob);
  prep_wo<<<512, 256, 0, stream>>>(W_O, Wot);
  prep_bqkv<<<12, 256, 0, stream>>>(b_Q, b_K, b_V, bqkv);

  ln_f32<<<4096, 256, 0, stream>>>(x, xn);
  // QKV: Q,K -> qk[4096][2048]; V -> vT[1024][4096] (transposed in epilogue)
  gemm_bt<128, 32, false, true, false, u16, float><<<dim3(32, 24), 256, 0, stream>>>(
      xn, Wqkv, bqkv, (const float*)nullptr, qk, vT, nullptr, nullptr,
      4096, 3072, 1024, 1024, 2048, 1024);
  attn_flash<<<1024, 256, 0, stream>>>(qk, vT);
  // attn-out: BN=64, BK=64 (round-0 config, non-atomic)
  gemm_bt<64, 64, false, false, false, float, float><<<dim3(32, 16), 256, 0, stream>>>(
      qk /*z in q half, lda=2048*/, Wot, b_O, x, rm, nullptr, nullptr, nullptr,
      4096, 1024, 1024, 2048, 1024, 1024);
  ln_f32<<<4096, 256, 0, stream>>>(rm, xn);
  gemm_bt<128, 32, true, false, false, u16, float><<<dim3(32, 32), 256, 0, stream>>>(
      xn, Wib, b_in, (const float*)nullptr, hbuf, nullptr, nullptr, nullptr,
      4096, 4096, 1024, 1024, 4096, 1024);
  // MLP-out: 128x128 tiles, non-atomic split-K=4 (1024 blocks = 4/CU).
  // z=0 -> f32 acc+bias into out; z=1..3 -> bf16 partials P1..P3.
  gemm_bt<128, 32, false, false, true, float, float><<<dim3(32, 8, 4), 256, 0, stream>>>(
      hbuf, Wob, b_out, (const float*)nullptr, out, P1, P2, P3,
      4096, 1024, 4096, 4096, 1024, 1024);
  // out += P1 + P2 + P3 + rm (residual)
  reduce_mlp<<<2048, 256, 0, stream>>>(out, P1, P2, P3, rm);
}

// Round 3
// 406.484 us; speedup vs baseline: 1.1590x; 1.0338x over previous
//
#include <hip/hip_runtime.h>

typedef unsigned short u16;
typedef __attribute__((ext_vector_type(8))) short short8;
typedef __attribute__((ext_vector_type(4))) unsigned short ushort4v;
typedef __attribute__((ext_vector_type(4))) float float4v;

__device__ __forceinline__ float bf2f(u16 u) {
  union { unsigned int i; float f; } c; c.i = ((unsigned int)u) << 16; return c.f;
}
__device__ __forceinline__ u16 f2bf(float f) {
  union { float f; unsigned int i; } c; c.f = f;
  unsigned int u = c.i;
  return (u16)((u + 0x7fffu + ((u >> 16) & 1u)) >> 16);
}
// 0.5x(1+tanh(c(x+0.044715x^3))) == x * sigmoid(2c(x+0.044715x^3))
//   == x / (1 + exp2(-(k1*x + k3*x^3))), k1 = 2c*log2(e), k3 = k1*0.044715
__device__ __forceinline__ float gelu_new(float x) {
  const float k1 = 2.30218776f;
  const float k3 = 0.10294233f;
  float x3 = x * x * x;
  float e = __builtin_amdgcn_exp2f(-(k1 * x + k3 * x3));
  return x / (1.0f + e);
}
__device__ __forceinline__ float ldres(const float* p) { return *p; }
__device__ __forceinline__ float ldres(const u16* p) { return bf2f(*p); }

__device__ __forceinline__ void gload_lds16(const u16* g, u16* l) {
  __builtin_amdgcn_global_load_lds(
      (const __attribute__((address_space(1))) unsigned int*)g,
      (__attribute__((address_space(3))) unsigned int*)l, 16, 0, 0);
}

// ---------------- prep kernels ----------------
__global__ void cvt_bf16(const float* __restrict__ src, u16* __restrict__ dst) {
  int t = blockIdx.x * 256 + threadIdx.x;
  float4v a = *(const float4v*)(src + (size_t)t * 8);
  float4v b = *(const float4v*)(src + (size_t)t * 8 + 4);
  short8 o;
#pragma unroll
  for (int j = 0; j < 4; ++j) o[j] = (short)f2bf(a[j]);
#pragma unroll
  for (int j = 0; j < 4; ++j) o[4 + j] = (short)f2bf(b[j]);
  *(short8*)(dst + (size_t)t * 8) = o;
}

// W_O [16,1024,64] f32 -> Wot[d, i*64+h] bf16
__global__ void prep_wo(const float* __restrict__ WO, u16* __restrict__ Wot) {
  int t = blockIdx.x * 256 + threadIdx.x;  // 0..131071
  int i = t >> 13;
  int d = (t >> 3) & 1023;
  int h0 = (t & 7) * 8;
  const float* src = WO + (size_t)i * 65536 + d * 64 + h0;
  float4v a = *(const float4v*)(src);
  float4v b = *(const float4v*)(src + 4);
  short8 o;
#pragma unroll
  for (int j = 0; j < 4; ++j) o[j] = (short)f2bf(a[j]);
#pragma unroll
  for (int j = 0; j < 4; ++j) o[4 + j] = (short)f2bf(b[j]);
  *(short8*)(Wot + (size_t)d * 1024 + i * 64 + h0) = o;
}

__global__ void prep_bqkv(const float* __restrict__ bQ, const float* __restrict__ bK,
                          const float* __restrict__ bV, float* __restrict__ bqkv) {
  int t = blockIdx.x * 256 + threadIdx.x;
  if (t < 3072)
    bqkv[t] = (t < 1024) ? bQ[t] : (t < 2048) ? bK[t - 1024] : bV[t - 2048];
}

// ---------------- layernorm (ln_pre): f32 in -> bf16 out ----------------
__global__ void ln_f32(const float* __restrict__ x, u16* __restrict__ y) {
  __shared__ float red1[4];
  __shared__ float red2[4];
  int token = blockIdx.x;
  int tid = threadIdx.x;
  int w = tid >> 6;
  const float* xr = x + (size_t)token * 1024;
  float4v v = *(const float4v*)(xr + tid * 4);
  float s = v[0] + v[1] + v[2] + v[3];
#pragma unroll
  for (int m = 32; m >= 1; m >>= 1) s += __shfl_xor(s, m);
  if ((tid & 63) == 0) red1[w] = s;
  __syncthreads();
  float mean = (red1[0] + red1[1] + red1[2] + red1[3]) * (1.0f / 1024.0f);
  float ss = 0.0f;
#pragma unroll
  for (int j = 0; j < 4; ++j) { v[j] -= mean; ss += v[j] * v[j]; }
#pragma unroll
  for (int m = 32; m >= 1; m >>= 1) ss += __shfl_xor(ss, m);
  if ((tid & 63) == 0) red2[w] = ss;
  __syncthreads();
  float ms = (red2[0] + red2[1] + red2[2] + red2[3]) * (1.0f / 1024.0f);
  float inv = 1.0f / sqrtf(ms + 1e-5f);
  ushort4v o;
#pragma unroll
  for (int j = 0; j < 4; ++j) o[j] = f2bf(v[j] * inv);
  *(ushort4v*)(y + (size_t)token * 1024 + tid * 4) = o;
}

// ---------------- GEMM: C[M,N] = A[M,K](bf16, stride lda) * Bw[N,K]^T ----------------
// LDS layout (rule #21 both-sides swizzle): LDS stays linear for global_load_lds;
// the *global source* segment is pre-swizzled (seg ^= row&(SEGS-1)) and the
// fragment ds_read XORs the same mask -> bank slot now depends on l16, killing
// the 16-way same-slot conflict of row-major BK=64 tiles.
// DBUF: T3 minimum 2-phase — issue next tile's global_load_lds into buf^1
// before computing buf, one __syncthreads per iter (its implicit
// vmcnt(0)+lgkmcnt(0) drain doubles as the prefetch fence).
// VSPLIT: cols >= 2048 are written transposed to vTout[(col-2048)*4096 + row].
template <int BN, int BK, bool GELU, bool VSPLIT, bool DBUF, typename TO, typename TR>
__global__ __launch_bounds__(256) void gemm_bt(
    const u16* __restrict__ A, const u16* __restrict__ Bw,
    const float* __restrict__ bias, const TR* __restrict__ resid,
    TO* __restrict__ C, u16* __restrict__ vTout, int M, int N, int K,
    int lda, int ldc) {
  constexpr int BM = 128;
  constexpr int SEGS = BK / 8;           // 16B chunks per tile row
  constexpr int SMASK = SEGS - 1;
  constexpr int FI = 4, FJ = BN / 32;
  constexpr int CA = BM * SEGS / 256;    // chunks per thread (A tile)
  constexpr int CB = BN * SEGS / 256;
  constexpr int NB = DBUF ? 2 : 1;
  __shared__ __align__(16) u16 As[NB][BM * BK];
  __shared__ __align__(16) u16 Bs[NB][BN * BK];
  const int tid = threadIdx.x;
  const int w = tid >> 6, lane = tid & 63;
  const int quad = lane >> 4, l16 = lane & 15;
  const int m0 = blockIdx.x * BM, n0 = blockIdx.y * BN;
  const int wm = (w >> 1) * 64, wn = (w & 1) * (BN / 2);
  const int rmask = l16 & SMASK;  // == row & SMASK for all fragment rows
  float4v acc[FI][FJ] = {};

  auto stage = [&](int buf, int k0) {
#pragma unroll
    for (int t = 0; t < CA; ++t) {
      int chunk = (w * CA + t) * 64 + lane;
      int row = chunk / SEGS, seg = chunk % SEGS;
      int sseg = seg ^ (row & SMASK);
      gload_lds16(A + (size_t)(m0 + row) * lda + k0 + sseg * 8,
                  As[buf] + (w * CA + t) * 512);
    }
#pragma unroll
    for (int t = 0; t < CB; ++t) {
      int chunk = (w * CB + t) * 64 + lane;
      int row = chunk / SEGS, seg = chunk % SEGS;
      int sseg = seg ^ (row & SMASK);
      gload_lds16(Bw + (size_t)(n0 + row) * K + k0 + sseg * 8,
                  Bs[buf] + (w * CB + t) * 512);
    }
  };
  auto compute = [&](int buf) {
#pragma unroll
    for (int kk = 0; kk < BK; kk += 32) {
      short8 a[FI], b[FJ];
#pragma unroll
      for (int fi = 0; fi < FI; ++fi)
        a[fi] = *(const short8*)(As[buf] + (wm + fi * 16 + l16) * BK +
                                 ((((kk >> 3) + quad) ^ rmask) << 3));
#pragma unroll
      for (int fj = 0; fj < FJ; ++fj)
        b[fj] = *(const short8*)(Bs[buf] + (wn + fj * 16 + l16) * BK +
                                 ((((kk >> 3) + quad) ^ rmask) << 3));
#pragma unroll
      for (int fi = 0; fi < FI; ++fi)
#pragma unroll
        for (int fj = 0; fj < FJ; ++fj)
          acc[fi][fj] = __builtin_amdgcn_mfma_f32_16x16x32_bf16(
              a[fi], b[fj], acc[fi][fj], 0, 0, 0);
    }
  };

  if constexpr (DBUF) {
    stage(0, 0);
    __syncthreads();  // drain prologue loads
    int cur = 0;
    for (int k0 = 0; k0 < K; k0 += BK) {
      if (k0 + BK < K) stage(cur ^ 1, k0 + BK);  // prefetch next tile
      compute(cur);                               // overlaps with loads in flight
      __syncthreads();  // drain prefetch + guard buf reuse
      cur ^= 1;
    }
  } else {
    for (int k0 = 0; k0 < K; k0 += BK) {
      __syncthreads();
      stage(0, k0);
      __syncthreads();
      compute(0);
    }
  }

#pragma unroll
  for (int fi = 0; fi < FI; ++fi) {
#pragma unroll
    for (int fj = 0; fj < FJ; ++fj) {
      int col = n0 + wn + fj * 16 + l16;
      float bv = bias ? bias[col] : 0.0f;
#pragma unroll
      for (int r = 0; r < 4; ++r) {
        int row = m0 + wm + fi * 16 + quad * 4 + r;
        float val = acc[fi][fj][r] + bv;
        if (resid) val += ldres(resid + (size_t)row * N + col);
        if (GELU) val = gelu_new(val);
        if (VSPLIT && col >= 2048) {
          vTout[(size_t)(col - 2048) * 4096 + row] = f2bf(val);
        } else if constexpr (sizeof(TO) == 2) {
          C[(size_t)row * ldc + col] = f2bf(val);
        } else {
          C[(size_t)row * ldc + col] = val;
        }
      }
    }
  }
}

// ---------------- single-pass flash attention (causal, online softmax, exp2) ----------------
// qk: [B*S, 2048] (q|k); vT: [1024][4096] = V transposed. z -> q half of qk.
// Grid: 1024 linear blocks; id = qtile_rev*32 + (head*2+b) so that id%8 groups
// all q-tiles of one (b,h) on one XCD (K/V stays in that XCD's 4MB L2).
__global__ __launch_bounds__(256) void attn_flash(u16* __restrict__ qk,
                                                  const u16* __restrict__ vT) {
  constexpr int PADK = 72;
  constexpr float C2 = 0.18033688011112042f;  // (1/8) * log2(e)
  __shared__ __align__(16) u16 Ks[64 * PADK];
  __shared__ __align__(16) u16 Vt[64 * PADK];
  __shared__ __align__(16) u16 Ps[4][16 * PADK];
  const int id = blockIdx.x;
  const int qt = 31 - (id >> 5);  // longest blocks first
  const int combo = id & 31;
  const int head = combo >> 1, b = combo & 1;
  const int tid = threadIdx.x;
  const int w = tid >> 6, lane = tid & 63;
  const int quad = lane >> 4, l16 = lane & 15;
  const int q0 = qt * 64;
  const size_t tokB = (size_t)b * 2048;

  short8 aq[2];
#pragma unroll
  for (int ks = 0; ks < 2; ++ks)
    aq[ks] = *(const short8*)(qk + (tokB + q0 + w * 16 + l16) * 2048 +
                              head * 64 + ks * 32 + quad * 8);

  const u16* kbase = qk + tokB * 2048 + 1024 + head * 64;   // + (kk0+row)*2048 + seg*8
  const u16* vbase = vT + (size_t)head * 64 * 4096 + tokB;  // + row*4096 + kk0 + seg*8

  float m_st[4] = {-1e30f, -1e30f, -1e30f, -1e30f};
  float l_st[4] = {0.f, 0.f, 0.f, 0.f};
  float4v o_acc[4] = {};

  for (int kt = 0; kt <= qt; ++kt) {
    const int kk0 = kt * 64;
    __syncthreads();
#pragma unroll
    for (int i = 0; i < 2; ++i) {
      int flat = tid * 2 + i;  // 0..511
      int row = flat >> 3, seg = flat & 7;
      *(short8*)(Ks + row * PADK + seg * 8) =
          *(const short8*)(kbase + (size_t)(kk0 + row) * 2048 + seg * 8);
      *(short8*)(Vt + row * PADK + seg * 8) =
          *(const short8*)(vbase + (size_t)row * 4096 + kk0 + seg * 8);
    }
    __syncthreads();

    float4v s[4];
#pragma unroll
    for (int fj = 0; fj < 4; ++fj) {
      float4v t = {0.f, 0.f, 0.f, 0.f};
#pragma unroll
      for (int ks = 0; ks < 2; ++ks) {
        short8 bk = *(const short8*)(Ks + (fj * 16 + l16) * PADK + ks * 32 + quad * 8);
        t = __builtin_amdgcn_mfma_f32_16x16x32_bf16(aq[ks], bk, t, 0, 0, 0);
      }
      s[fj] = t;
    }
#pragma unroll
    for (int fj = 0; fj < 4; ++fj)
#pragma unroll
      for (int r = 0; r < 4; ++r) s[fj][r] *= C2;
    if (kt == qt) {
#pragma unroll
      for (int fj = 0; fj < 4; ++fj) {
        int col = kk0 + fj * 16 + l16;
#pragma unroll
        for (int r = 0; r < 4; ++r) {
          int row = q0 + w * 16 + quad * 4 + r;
          if (col > row) s[fj][r] = -1e30f;
        }
      }
    }
    float mx[4];
#pragma unroll
    for (int r = 0; r < 4; ++r) {
      float m = s[0][r];
#pragma unroll
      for (int fj = 1; fj < 4; ++fj) m = fmaxf(m, s[fj][r]);
      m = fmaxf(m, __shfl_xor(m, 1));
      m = fmaxf(m, __shfl_xor(m, 2));
      m = fmaxf(m, __shfl_xor(m, 4));
      m = fmaxf(m, __shfl_xor(m, 8));
      mx[r] = m;
    }
    float alpha[4];
#pragma unroll
    for (int r = 0; r < 4; ++r) {
      float mnew = fmaxf(m_st[r], mx[r]);
      alpha[r] = __builtin_amdgcn_exp2f(m_st[r] - mnew);
      m_st[r] = mnew;
    }
    float rs[4] = {0.f, 0.f, 0.f, 0.f};
#pragma unroll
    for (int fj = 0; fj < 4; ++fj)
#pragma unroll
      for (int r = 0; r < 4; ++r) {
        float pv = __builtin_amdgcn_exp2f(s[fj][r] - m_st[r]);
        s[fj][r] = pv;
        rs[r] += pv;
      }
#pragma unroll
    for (int r = 0; r < 4; ++r) {
      float t = rs[r];
      t += __shfl_xor(t, 1);
      t += __shfl_xor(t, 2);
      t += __shfl_xor(t, 4);
      t += __shfl_xor(t, 8);
      l_st[r] = l_st[r] * alpha[r] + t;
    }
#pragma unroll
    for (int fj = 0; fj < 4; ++fj)
#pragma unroll
      for (int r = 0; r < 4; ++r) o_acc[fj][r] *= alpha[r];
#pragma unroll
    for (int fj = 0; fj < 4; ++fj)
#pragma unroll
      for (int r = 0; r < 4; ++r)
        Ps[w][(quad * 4 + r) * PADK + fj * 16 + l16] = f2bf(s[fj][r]);
    short8 ap[2];
#pragma unroll
    for (int ks = 0; ks < 2; ++ks)
      ap[ks] = *(const short8*)(&Ps[w][l16 * PADK + ks * 32 + quad * 8]);
#pragma unroll
    for (int fj = 0; fj < 4; ++fj)
#pragma unroll
      for (int ks = 0; ks < 2; ++ks) {
        short8 bv = *(const short8*)(Vt + (fj * 16 + l16) * PADK + ks * 32 + quad * 8);
        o_acc[fj] = __builtin_amdgcn_mfma_f32_16x16x32_bf16(ap[ks], bv, o_acc[fj], 0, 0, 0);
      }
  }
#pragma unroll
  for (int r = 0; r < 4; ++r) {
    float inv = 1.0f / l_st[r];
    int row = q0 + w * 16 + quad * 4 + r;
#pragma unroll
    for (int fj = 0; fj < 4; ++fj)
      qk[(tokB + row) * 2048 + head * 64 + fj * 16 + l16] =
          f2bf(o_acc[fj][r] * inv);
  }
}

// ---------------- launcher ----------------
extern "C" void kernel_launch(void* const* d_in, const int* in_sizes, int n_in,
                              void* d_out, int out_size, void* d_ws, size_t ws_size,
                              hipStream_t stream) {
  const float* x = (const float*)d_in[0];
  const float* W_Q = (const float*)d_in[1];
  const float* W_K = (const float*)d_in[2];
  const float* W_V = (const float*)d_in[3];
  const float* W_O = (const float*)d_in[4];
  const float* b_Q = (const float*)d_in[5];
  const float* b_K = (const float*)d_in[6];
  const float* b_V = (const float*)d_in[7];
  const float* b_O = (const float*)d_in[8];
  const float* W_in = (const float*)d_in[9];
  const float* b_in = (const float*)d_in[10];
  const float* W_out = (const float*)d_in[11];
  const float* b_out = (const float*)d_in[12];
  float* out = (float*)d_out;

  char* ws = (char*)d_ws;
  u16* Wqkv = (u16*)(ws);                 // [0, 6291456)
  u16* Wot  = (u16*)(ws + 6291456);       // [6291456, 8388608)
  u16* Wib  = (u16*)(ws + 8388608);       // [8388608, 16777216)
  u16* Wob  = (u16*)(ws + 16777216);      // [16777216, 25165824)
  float* bqkv = (float*)(ws + 25165824);  // [25165824, 25178112)
  u16* xn   = (u16*)(ws + 25178112);      // [25178112, 33566720)
  u16* qk   = (u16*)(ws + 33566720);      // [33566720, 50343936)  4096*2048 bf16
  u16* vT   = (u16*)(ws + 50343936);      // [50343936, 58732544)  1024*4096 bf16
  u16* hbuf = (u16*)(ws + 33566720);      // overlays qk+vT, 4096*4096, ends 67121152
  float* rm = (float*)(ws + 67121152);    // [67121152, 83898368)

  cvt_bf16<<<512, 256, 0, stream>>>(W_Q, Wqkv);
  cvt_bf16<<<512, 256, 0, stream>>>(W_K, Wqkv + 1048576);
  cvt_bf16<<<512, 256, 0, stream>>>(W_V, Wqkv + 2097152);
  cvt_bf16<<<2048, 256, 0, stream>>>(W_in, Wib);
  cvt_bf16<<<2048, 256, 0, stream>>>(W_out, Wob);
  prep_wo<<<512, 256, 0, stream>>>(W_O, Wot);
  prep_bqkv<<<12, 256, 0, stream>>>(b_Q, b_K, b_V, bqkv);

  ln_f32<<<4096, 256, 0, stream>>>(x, xn);
  // QKV: Q,K -> qk[4096][2048]; V -> vT[1024][4096] (transposed in epilogue)
  // BK=64 + swizzle, single-buffered (768 blocks = 3/CU).
  gemm_bt<128, 64, false, true, false, u16, float><<<dim3(32, 24), 256, 0, stream>>>(
      xn, Wqkv, bqkv, (const float*)nullptr, qk, vT, 4096, 3072, 1024, 1024, 2048);
  attn_flash<<<1024, 256, 0, stream>>>(qk, vT);
  // attn-out: BN=64/BK=64 + swizzle + prefetch dbuf (512 blocks = 2/CU).
  gemm_bt<64, 64, false, false, true, float, float><<<dim3(32, 16), 256, 0, stream>>>(
      qk /*z in q half, lda=2048*/, Wot, b_O, x, rm, nullptr, 4096, 1024, 1024, 2048, 1024);
  ln_f32<<<4096, 256, 0, stream>>>(rm, xn);
  // MLP-in: BK=64 + swizzle, single-buffered (1024 blocks = 4/CU).
  gemm_bt<128, 64, true, false, false, u16, float><<<dim3(32, 32), 256, 0, stream>>>(
      xn, Wib, b_in, (const float*)nullptr, hbuf, nullptr, 4096, 4096, 1024, 1024, 4096);
  // MLP-out: BN=64/BK=64 + swizzle + prefetch dbuf (512 blocks = 2/CU).
  gemm_bt<64, 64, false, false, true, float, float><<<dim3(32, 16), 256, 0, stream>>>(
      hbuf, Wob, b_out, rm, out, nullptr, 4096, 1024, 4096, 4096, 1024);
}

// Round 4
// 366.486 us; speedup vs baseline: 1.2855x; 1.1091x over previous
//
#include <hip/hip_runtime.h>

typedef unsigned short u16;
typedef __attribute__((ext_vector_type(8))) short short8;
typedef __attribute__((ext_vector_type(4))) unsigned short ushort4v;
typedef __attribute__((ext_vector_type(4))) float float4v;

__device__ __forceinline__ float bf2f(u16 u) {
  union { unsigned int i; float f; } c; c.i = ((unsigned int)u) << 16; return c.f;
}
__device__ __forceinline__ u16 f2bf(float f) {
  union { float f; unsigned int i; } c; c.f = f;
  unsigned int u = c.i;
  return (u16)((u + 0x7fffu + ((u >> 16) & 1u)) >> 16);
}
// packed f32x2 -> bf16x2 (RNE), lo = bf16(a), hi = bf16(b)
__device__ __forceinline__ unsigned int cvt_pk_bf16(float a, float b) {
  unsigned int r;
  asm("v_cvt_pk_bf16_f32 %0, %1, %2" : "=v"(r) : "v"(a), "v"(b));
  return r;
}
// 0.5x(1+tanh(c(x+0.044715x^3))) == x * sigmoid(2c(x+0.044715x^3))
//   == x / (1 + exp2(-(k1*x + k3*x^3))), k1 = 2c*log2(e), k3 = k1*0.044715
__device__ __forceinline__ float gelu_new(float x) {
  const float k1 = 2.30218776f;
  const float k3 = 0.10294233f;
  float x3 = x * x * x;
  float e = __builtin_amdgcn_exp2f(-(k1 * x + k3 * x3));
  return x / (1.0f + e);
}
__device__ __forceinline__ float ldres(const float* p) { return *p; }
__device__ __forceinline__ float ldres(const u16* p) { return bf2f(*p); }

__device__ __forceinline__ void gload_lds16(const u16* g, u16* l) {
  __builtin_amdgcn_global_load_lds(
      (const __attribute__((address_space(1))) unsigned int*)g,
      (__attribute__((address_space(3))) unsigned int*)l, 16, 0, 0);
}

// ---------------- prep kernels ----------------
// one launch converts all 5 f32 weight blobs to bf16
__global__ void cvt_bf16_multi(const float* __restrict__ s0, const float* __restrict__ s1,
                               const float* __restrict__ s2, const float* __restrict__ s3,
                               const float* __restrict__ s4, u16* __restrict__ d0,
                               u16* __restrict__ d1, u16* __restrict__ d2,
                               u16* __restrict__ d3, u16* __restrict__ d4) {
  int bid = blockIdx.x;
  const float* src; u16* dst; int base;
  if (bid < 512)       { src = s0; dst = d0; base = 0; }
  else if (bid < 1024) { src = s1; dst = d1; base = 512; }
  else if (bid < 1536) { src = s2; dst = d2; base = 1024; }
  else if (bid < 3584) { src = s3; dst = d3; base = 1536; }
  else                 { src = s4; dst = d4; base = 3584; }
  int t = (bid - base) * 256 + threadIdx.x;
  float4v a = *(const float4v*)(src + (size_t)t * 8);
  float4v b = *(const float4v*)(src + (size_t)t * 8 + 4);
  short8 o;
#pragma unroll
  for (int j = 0; j < 4; ++j) o[j] = (short)f2bf(a[j]);
#pragma unroll
  for (int j = 0; j < 4; ++j) o[4 + j] = (short)f2bf(b[j]);
  *(short8*)(dst + (size_t)t * 8) = o;
}

// W_O [16,1024,64] f32 -> Wot[d, i*64+h] bf16
__global__ void prep_wo(const float* __restrict__ WO, u16* __restrict__ Wot) {
  int t = blockIdx.x * 256 + threadIdx.x;  // 0..131071
  int i = t >> 13;
  int d = (t >> 3) & 1023;
  int h0 = (t & 7) * 8;
  const float* src = WO + (size_t)i * 65536 + d * 64 + h0;
  float4v a = *(const float4v*)(src);
  float4v b = *(const float4v*)(src + 4);
  short8 o;
#pragma unroll
  for (int j = 0; j < 4; ++j) o[j] = (short)f2bf(a[j]);
#pragma unroll
  for (int j = 0; j < 4; ++j) o[4 + j] = (short)f2bf(b[j]);
  *(short8*)(Wot + (size_t)d * 1024 + i * 64 + h0) = o;
}

__global__ void prep_bqkv(const float* __restrict__ bQ, const float* __restrict__ bK,
                          const float* __restrict__ bV, float* __restrict__ bqkv) {
  int t = blockIdx.x * 256 + threadIdx.x;
  if (t < 3072)
    bqkv[t] = (t < 1024) ? bQ[t] : (t < 2048) ? bK[t - 1024] : bV[t - 2048];
}

// ---------------- layernorm (ln_pre): f32 in -> bf16 out ----------------
__global__ void ln_f32(const float* __restrict__ x, u16* __restrict__ y) {
  __shared__ float red1[4];
  __shared__ float red2[4];
  int token = blockIdx.x;
  int tid = threadIdx.x;
  int w = tid >> 6;
  const float* xr = x + (size_t)token * 1024;
  float4v v = *(const float4v*)(xr + tid * 4);
  float s = v[0] + v[1] + v[2] + v[3];
#pragma unroll
  for (int m = 32; m >= 1; m >>= 1) s += __shfl_xor(s, m);
  if ((tid & 63) == 0) red1[w] = s;
  __syncthreads();
  float mean = (red1[0] + red1[1] + red1[2] + red1[3]) * (1.0f / 1024.0f);
  float ss = 0.0f;
#pragma unroll
  for (int j = 0; j < 4; ++j) { v[j] -= mean; ss += v[j] * v[j]; }
#pragma unroll
  for (int m = 32; m >= 1; m >>= 1) ss += __shfl_xor(ss, m);
  if ((tid & 63) == 0) red2[w] = ss;
  __syncthreads();
  float ms = (red2[0] + red2[1] + red2[2] + red2[3]) * (1.0f / 1024.0f);
  float inv = 1.0f / sqrtf(ms + 1e-5f);
  ushort4v o;
#pragma unroll
  for (int j = 0; j < 4; ++j) o[j] = f2bf(v[j] * inv);
  *(ushort4v*)(y + (size_t)token * 1024 + tid * 4) = o;
}

// ---------------- GEMM: C[M,N] = A[M,K](bf16, stride lda) * Bw[N,K]^T ----------------
// LDS layout (rule #21 both-sides swizzle): LDS stays linear for global_load_lds;
// the *global source* segment is pre-swizzled (seg ^= row&(SEGS-1)) and the
// fragment ds_read XORs the same mask -> bank slot depends on l16, killing
// the 16-way same-slot conflict of row-major BK=64 tiles.
// DBUF: issue next tile's global_load_lds into buf^1 before computing buf.
// VSPLIT: cols >= 2048 go transposed to vTout; cols < 1024 (= Q) are
// pre-scaled by (1/8)*log2e so attention's softmax works in log2 domain.
template <int BN, int BK, bool GELU, bool VSPLIT, bool DBUF, typename TO, typename TR>
__global__ __launch_bounds__(256) void gemm_bt(
    const u16* __restrict__ A, const u16* __restrict__ Bw,
    const float* __restrict__ bias, const TR* __restrict__ resid,
    TO* __restrict__ C, u16* __restrict__ vTout, int M, int N, int K,
    int lda, int ldc) {
  constexpr int BM = 128;
  constexpr int SEGS = BK / 8;           // 16B chunks per tile row
  constexpr int SMASK = SEGS - 1;
  constexpr int FI = 4, FJ = BN / 32;
  constexpr int CA = BM * SEGS / 256;    // chunks per thread (A tile)
  constexpr int CB = BN * SEGS / 256;
  constexpr int NB = DBUF ? 2 : 1;
  __shared__ __align__(16) u16 As[NB][BM * BK];
  __shared__ __align__(16) u16 Bs[NB][BN * BK];
  const int tid = threadIdx.x;
  const int w = tid >> 6, lane = tid & 63;
  const int quad = lane >> 4, l16 = lane & 15;
  const int m0 = blockIdx.x * BM, n0 = blockIdx.y * BN;
  const int wm = (w >> 1) * 64, wn = (w & 1) * (BN / 2);
  const int rmask = l16 & SMASK;  // == row & SMASK for all fragment rows
  float4v acc[FI][FJ] = {};

  auto stage = [&](int buf, int k0) {
#pragma unroll
    for (int t = 0; t < CA; ++t) {
      int chunk = (w * CA + t) * 64 + lane;
      int row = chunk / SEGS, seg = chunk % SEGS;
      int sseg = seg ^ (row & SMASK);
      gload_lds16(A + (size_t)(m0 + row) * lda + k0 + sseg * 8,
                  As[buf] + (w * CA + t) * 512);
    }
#pragma unroll
    for (int t = 0; t < CB; ++t) {
      int chunk = (w * CB + t) * 64 + lane;
      int row = chunk / SEGS, seg = chunk % SEGS;
      int sseg = seg ^ (row & SMASK);
      gload_lds16(Bw + (size_t)(n0 + row) * K + k0 + sseg * 8,
                  Bs[buf] + (w * CB + t) * 512);
    }
  };
  auto compute = [&](int buf) {
#pragma unroll
    for (int kk = 0; kk < BK; kk += 32) {
      short8 a[FI], b[FJ];
#pragma unroll
      for (int fi = 0; fi < FI; ++fi)
        a[fi] = *(const short8*)(As[buf] + (wm + fi * 16 + l16) * BK +
                                 ((((kk >> 3) + quad) ^ rmask) << 3));
#pragma unroll
      for (int fj = 0; fj < FJ; ++fj)
        b[fj] = *(const short8*)(Bs[buf] + (wn + fj * 16 + l16) * BK +
                                 ((((kk >> 3) + quad) ^ rmask) << 3));
#pragma unroll
      for (int fi = 0; fi < FI; ++fi)
#pragma unroll
        for (int fj = 0; fj < FJ; ++fj)
          acc[fi][fj] = __builtin_amdgcn_mfma_f32_16x16x32_bf16(
              a[fi], b[fj], acc[fi][fj], 0, 0, 0);
    }
  };

  if constexpr (DBUF) {
    stage(0, 0);
    __syncthreads();  // drain prologue loads
    int cur = 0;
    for (int k0 = 0; k0 < K; k0 += BK) {
      if (k0 + BK < K) stage(cur ^ 1, k0 + BK);  // prefetch next tile
      compute(cur);                               // overlaps with loads in flight
      __syncthreads();  // drain prefetch + guard buf reuse
      cur ^= 1;
    }
  } else {
    for (int k0 = 0; k0 < K; k0 += BK) {
      __syncthreads();
      stage(0, k0);
      __syncthreads();
      compute(0);
    }
  }

#pragma unroll
  for (int fi = 0; fi < FI; ++fi) {
#pragma unroll
    for (int fj = 0; fj < FJ; ++fj) {
      int col = n0 + wn + fj * 16 + l16;
      float bv = bias ? bias[col] : 0.0f;
#pragma unroll
      for (int r = 0; r < 4; ++r) {
        int row = m0 + wm + fi * 16 + quad * 4 + r;
        float val = acc[fi][fj][r] + bv;
        if (resid) val += ldres(resid + (size_t)row * N + col);
        if (GELU) val = gelu_new(val);
        if (VSPLIT && col < 1024) val *= 0.18033688011112042f;  // Q pre-scale
        if (VSPLIT && col >= 2048) {
          vTout[(size_t)(col - 2048) * 4096 + row] = f2bf(val);
        } else if constexpr (sizeof(TO) == 2) {
          C[(size_t)row * ldc + col] = f2bf(val);
        } else {
          C[(size_t)row * ldc + col] = val;
        }
      }
    }
  }
}

// ---------------- single-pass flash attention (causal, online softmax, exp2) ----------------
// qk: [B*S, 2048] (q|k), Q pre-scaled by (1/8)log2e; vT: [1024][4096] = V^T.
// z -> q half of qk. Grid: id%8 groups all q-tiles of one (b,h) on one XCD.
// VALU diet: row-sum l via ones-column MFMA (o5), defer-max (THR=10 log2),
// cvt_pk_bf16 P-store, T14 reg-prefetch of next K/V tile, setprio on MFMA.
__global__ __launch_bounds__(256) void attn_flash(u16* __restrict__ qk,
                                                  const u16* __restrict__ vT) {
  constexpr int PADK = 72;
  constexpr float THR2 = 10.0f;  // defer-max threshold, log2 domain (P <= 2^10)
  __shared__ __align__(16) u16 Ks[64 * PADK];
  __shared__ __align__(16) u16 Vt[64 * PADK];
  __shared__ __align__(16) u16 Ps[4][16 * PADK];
  const int id = blockIdx.x;
  const int qt = 31 - (id >> 5);  // longest blocks first
  const int combo = id & 31;
  const int head = combo >> 1, b = combo & 1;
  const int tid = threadIdx.x;
  const int w = tid >> 6, lane = tid & 63;
  const int quad = lane >> 4, l16 = lane & 15;
  const int q0 = qt * 64;
  const size_t tokB = (size_t)b * 2048;

  short8 aq[2];
#pragma unroll
  for (int ks = 0; ks < 2; ++ks)
    aq[ks] = *(const short8*)(qk + (tokB + q0 + w * 16 + l16) * 2048 +
                              head * 64 + ks * 32 + quad * 8);

  const u16* kbase = qk + tokB * 2048 + 1024 + head * 64;   // + (kk0+row)*2048 + seg*8
  const u16* vbase = vT + (size_t)head * 64 * 4096 + tokB;  // + row*4096 + kk0 + seg*8

  // ones-column B-fragment: col 0 of a 16-col tile = 1.0, rest 0.
  short8 bones = {};
  if (l16 == 0) {
#pragma unroll
    for (int j = 0; j < 8; ++j) bones[j] = (short)0x3F80;
  }

  float m_st[4] = {-1e30f, -1e30f, -1e30f, -1e30f};
  float4v o_acc[4] = {};
  float4v o5 = {0.f, 0.f, 0.f, 0.f};  // row-sums (col 0 lanes only)

  // staging geometry: each thread owns 2 consecutive 16B segs of one row
  const int srow = tid >> 2;
  const int sseg = (tid & 3) * 2;
  const u16* kptr = kbase + (size_t)srow * 2048 + sseg * 8;
  const u16* vptr = vbase + (size_t)srow * 4096 + sseg * 8;
  u16* ksl = Ks + srow * PADK + sseg * 8;
  u16* vsl = Vt + srow * PADK + sseg * 8;

  // prologue: prefetch tile 0 into regs
  short8 pk0 = *(const short8*)(kptr);
  short8 pk1 = *(const short8*)(kptr + 8);
  short8 pv0 = *(const short8*)(vptr);
  short8 pv1 = *(const short8*)(vptr + 8);

  for (int kt = 0; kt <= qt; ++kt) {
    const int kk0 = kt * 64;
    __syncthreads();  // previous compute done reading Ks/Vt
    *(short8*)(ksl) = pk0;
    *(short8*)(ksl + 8) = pk1;
    *(short8*)(vsl) = pv0;
    *(short8*)(vsl + 8) = pv1;
    __syncthreads();  // LDS writes visible
    if (kt < qt) {    // T14: issue next-tile loads; they fly during compute
      const u16* kp = kptr + (size_t)(kk0 + 64) * 2048;
      const u16* vp = vptr + kk0 + 64;
      pk0 = *(const short8*)(kp);
      pk1 = *(const short8*)(kp + 8);
      pv0 = *(const short8*)(vp);
      pv1 = *(const short8*)(vp + 8);
    }

    float4v s[4];
    __builtin_amdgcn_s_setprio(1);
#pragma unroll
    for (int fj = 0; fj < 4; ++fj) {
      float4v t = {0.f, 0.f, 0.f, 0.f};
#pragma unroll
      for (int ks = 0; ks < 2; ++ks) {
        short8 bk = *(const short8*)(Ks + (fj * 16 + l16) * PADK + ks * 32 + quad * 8);
        t = __builtin_amdgcn_mfma_f32_16x16x32_bf16(aq[ks], bk, t, 0, 0, 0);
      }
      s[fj] = t;
    }
    __builtin_amdgcn_s_setprio(0);
    if (kt == qt) {
#pragma unroll
      for (int fj = 0; fj < 4; ++fj) {
        int col = kk0 + fj * 16 + l16;
#pragma unroll
        for (int r = 0; r < 4; ++r) {
          int row = q0 + w * 16 + quad * 4 + r;
          if (col > row) s[fj][r] = -1e30f;
        }
      }
    }
    float mx[4];
#pragma unroll
    for (int r = 0; r < 4; ++r) {
      float m = fmaxf(fmaxf(s[0][r], s[1][r]), fmaxf(s[2][r], s[3][r]));
      m = fmaxf(m, __shfl_xor(m, 1));
      m = fmaxf(m, __shfl_xor(m, 2));
      m = fmaxf(m, __shfl_xor(m, 4));
      m = fmaxf(m, __shfl_xor(m, 8));
      mx[r] = m;
    }
    // defer-max: only rescale when the max grew by more than THR2
    bool need = false;
#pragma unroll
    for (int r = 0; r < 4; ++r) need |= (mx[r] > m_st[r] + THR2);
    if (__any(need)) {
#pragma unroll
      for (int r = 0; r < 4; ++r) {
        float mnew = fmaxf(m_st[r], mx[r]);
        float al = __builtin_amdgcn_exp2f(m_st[r] - mnew);
        m_st[r] = mnew;
        o5[r] *= al;
#pragma unroll
        for (int fj = 0; fj < 4; ++fj) o_acc[fj][r] *= al;
      }
    }
    // P = exp2(s - m), packed bf16 convert, store to Ps
#pragma unroll
    for (int fj = 0; fj < 4; ++fj) {
#pragma unroll
      for (int r = 0; r < 4; r += 2) {
        float e0 = __builtin_amdgcn_exp2f(s[fj][r] - m_st[r]);
        float e1 = __builtin_amdgcn_exp2f(s[fj][r + 1] - m_st[r + 1]);
        unsigned int pp = cvt_pk_bf16(e0, e1);
        Ps[w][(quad * 4 + r) * PADK + fj * 16 + l16] = (u16)pp;
        Ps[w][(quad * 4 + r + 1) * PADK + fj * 16 + l16] = (u16)(pp >> 16);
      }
    }
    short8 ap[2];
#pragma unroll
    for (int ks = 0; ks < 2; ++ks)
      ap[ks] = *(const short8*)(&Ps[w][l16 * PADK + ks * 32 + quad * 8]);
    __builtin_amdgcn_s_setprio(1);
#pragma unroll
    for (int fj = 0; fj < 4; ++fj)
#pragma unroll
      for (int ks = 0; ks < 2; ++ks) {
        short8 bv = *(const short8*)(Vt + (fj * 16 + l16) * PADK + ks * 32 + quad * 8);
        o_acc[fj] = __builtin_amdgcn_mfma_f32_16x16x32_bf16(ap[ks], bv, o_acc[fj], 0, 0, 0);
      }
#pragma unroll
    for (int ks = 0; ks < 2; ++ks)
      o5 = __builtin_amdgcn_mfma_f32_16x16x32_bf16(ap[ks], bones, o5, 0, 0, 0);
    __builtin_amdgcn_s_setprio(0);
  }
#pragma unroll
  for (int r = 0; r < 4; ++r) {
    float lsum = __shfl(o5[r], lane & 48);  // broadcast col-0 lane of the quad
    float inv = 1.0f / lsum;
    int row = q0 + w * 16 + quad * 4 + r;
#pragma unroll
    for (int fj = 0; fj < 4; ++fj)
      qk[(tokB + row) * 2048 + head * 64 + fj * 16 + l16] =
          f2bf(o_acc[fj][r] * inv);
  }
}

// ---------------- launcher ----------------
extern "C" void kernel_launch(void* const* d_in, const int* in_sizes, int n_in,
                              void* d_out, int out_size, void* d_ws, size_t ws_size,
                              hipStream_t stream) {
  const float* x = (const float*)d_in[0];
  const float* W_Q = (const float*)d_in[1];
  const float* W_K = (const float*)d_in[2];
  const float* W_V = (const float*)d_in[3];
  const float* W_O = (const float*)d_in[4];
  const float* b_Q = (const float*)d_in[5];
  const float* b_K = (const float*)d_in[6];
  const float* b_V = (const float*)d_in[7];
  const float* b_O = (const float*)d_in[8];
  const float* W_in = (const float*)d_in[9];
  const float* b_in = (const float*)d_in[10];
  const float* W_out = (const float*)d_in[11];
  const float* b_out = (const float*)d_in[12];
  float* out = (float*)d_out;

  char* ws = (char*)d_ws;
  u16* Wqkv = (u16*)(ws);                 // [0, 6291456)
  u16* Wot  = (u16*)(ws + 6291456);       // [6291456, 8388608)
  u16* Wib  = (u16*)(ws + 8388608);       // [8388608, 16777216)
  u16* Wob  = (u16*)(ws + 16777216);      // [16777216, 25165824)
  float* bqkv = (float*)(ws + 25165824);  // [25165824, 25178112)
  u16* xn   = (u16*)(ws + 25178112);      // [25178112, 33566720)
  u16* qk   = (u16*)(ws + 33566720);      // [33566720, 50343936)  4096*2048 bf16
  u16* vT   = (u16*)(ws + 50343936);      // [50343936, 58732544)  1024*4096 bf16
  u16* hbuf = (u16*)(ws + 33566720);      // overlays qk+vT, 4096*4096, ends 67121152
  float* rm = (float*)(ws + 67121152);    // [67121152, 83898368)

  cvt_bf16_multi<<<5632, 256, 0, stream>>>(W_Q, W_K, W_V, W_in, W_out,
                                           Wqkv, Wqkv + 1048576, Wqkv + 2097152,
                                           Wib, Wob);
  prep_wo<<<512, 256, 0, stream>>>(W_O, Wot);
  prep_bqkv<<<12, 256, 0, stream>>>(b_Q, b_K, b_V, bqkv);

  ln_f32<<<4096, 256, 0, stream>>>(x, xn);
  // QKV: Q,K -> qk[4096][2048] (Q pre-scaled); V -> vT[1024][4096]
  gemm_bt<128, 64, false, true, false, u16, float><<<dim3(32, 24), 256, 0, stream>>>(
      xn, Wqkv, bqkv, (const float*)nullptr, qk, vT, 4096, 3072, 1024, 1024, 2048);
  attn_flash<<<1024, 256, 0, stream>>>(qk, vT);
  // attn-out: BN=64/BK=64 + swizzle + prefetch dbuf (512 blocks = 2/CU).
  gemm_bt<64, 64, false, false, true, float, float><<<dim3(32, 16), 256, 0, stream>>>(
      qk /*z in q half, lda=2048*/, Wot, b_O, x, rm, nullptr, 4096, 1024, 1024, 2048, 1024);
  ln_f32<<<4096, 256, 0, stream>>>(rm, xn);
  // MLP-in: BK=64 + swizzle, single-buffered (1024 blocks = 4/CU).
  gemm_bt<128, 64, true, false, false, u16, float><<<dim3(32, 32), 256, 0, stream>>>(
      xn, Wib, b_in, (const float*)nullptr, hbuf, nullptr, 4096, 4096, 1024, 1024, 4096);
  // MLP-out: BN=64/BK=64 + swizzle + prefetch dbuf (512 blocks = 2/CU).
  gemm_bt<64, 64, false, false, true, float, float><<<dim3(32, 16), 256, 0, stream>>>(
      hbuf, Wob, b_out, rm, out, nullptr, 4096, 1024, 4096, 4096, 1024);
}

// Round 5
// 354.675 us; speedup vs baseline: 1.3283x; 1.0333x over previous
//
#include <hip/hip_runtime.h>

typedef unsigned short u16;
typedef __attribute__((ext_vector_type(8))) short short8;
typedef __attribute__((ext_vector_type(4))) unsigned short ushort4v;
typedef __attribute__((ext_vector_type(4))) float float4v;

__device__ __forceinline__ float bf2f(u16 u) {
  union { unsigned int i; float f; } c; c.i = ((unsigned int)u) << 16; return c.f;
}
__device__ __forceinline__ u16 f2bf(float f) {
  union { float f; unsigned int i; } c; c.f = f;
  unsigned int u = c.i;
  return (u16)((u + 0x7fffu + ((u >> 16) & 1u)) >> 16);
}
// packed f32x2 -> bf16x2 (RNE), lo = bf16(a), hi = bf16(b)
__device__ __forceinline__ unsigned int cvt_pk_bf16(float a, float b) {
  unsigned int r;
  asm("v_cvt_pk_bf16_f32 %0, %1, %2" : "=v"(r) : "v"(a), "v"(b));
  return r;
}
// 0.5x(1+tanh(c(x+0.044715x^3))) == x * sigmoid(2c(x+0.044715x^3))
//   == x / (1 + exp2(-(k1*x + k3*x^3))), k1 = 2c*log2(e), k3 = k1*0.044715
__device__ __forceinline__ float gelu_new(float x) {
  const float k1 = 2.30218776f;
  const float k3 = 0.10294233f;
  float x3 = x * x * x;
  float e = __builtin_amdgcn_exp2f(-(k1 * x + k3 * x3));
  return x / (1.0f + e);
}
__device__ __forceinline__ float ldres(const float* p) { return *p; }
__device__ __forceinline__ float ldres(const u16* p) { return bf2f(*p); }

__device__ __forceinline__ void gload_lds16(const u16* g, u16* l) {
  __builtin_amdgcn_global_load_lds(
      (const __attribute__((address_space(1))) unsigned int*)g,
      (__attribute__((address_space(3))) unsigned int*)l, 16, 0, 0);
}

// ---------------- prep kernels ----------------
// one launch converts all 5 f32 weight blobs to bf16
__global__ void cvt_bf16_multi(const float* __restrict__ s0, const float* __restrict__ s1,
                               const float* __restrict__ s2, const float* __restrict__ s3,
                               const float* __restrict__ s4, u16* __restrict__ d0,
                               u16* __restrict__ d1, u16* __restrict__ d2,
                               u16* __restrict__ d3, u16* __restrict__ d4) {
  int bid = blockIdx.x;
  const float* src; u16* dst; int base;
  if (bid < 512)       { src = s0; dst = d0; base = 0; }
  else if (bid < 1024) { src = s1; dst = d1; base = 512; }
  else if (bid < 1536) { src = s2; dst = d2; base = 1024; }
  else if (bid < 3584) { src = s3; dst = d3; base = 1536; }
  else                 { src = s4; dst = d4; base = 3584; }
  int t = (bid - base) * 256 + threadIdx.x;
  float4v a = *(const float4v*)(src + (size_t)t * 8);
  float4v b = *(const float4v*)(src + (size_t)t * 8 + 4);
  short8 o;
#pragma unroll
  for (int j = 0; j < 4; ++j) o[j] = (short)f2bf(a[j]);
#pragma unroll
  for (int j = 0; j < 4; ++j) o[4 + j] = (short)f2bf(b[j]);
  *(short8*)(dst + (size_t)t * 8) = o;
}

// W_O [16,1024,64] f32 -> Wot[d, i*64+h] bf16
__global__ void prep_wo(const float* __restrict__ WO, u16* __restrict__ Wot) {
  int t = blockIdx.x * 256 + threadIdx.x;  // 0..131071
  int i = t >> 13;
  int d = (t >> 3) & 1023;
  int h0 = (t & 7) * 8;
  const float* src = WO + (size_t)i * 65536 + d * 64 + h0;
  float4v a = *(const float4v*)(src);
  float4v b = *(const float4v*)(src + 4);
  short8 o;
#pragma unroll
  for (int j = 0; j < 4; ++j) o[j] = (short)f2bf(a[j]);
#pragma unroll
  for (int j = 0; j < 4; ++j) o[4 + j] = (short)f2bf(b[j]);
  *(short8*)(Wot + (size_t)d * 1024 + i * 64 + h0) = o;
}

__global__ void prep_bqkv(const float* __restrict__ bQ, const float* __restrict__ bK,
                          const float* __restrict__ bV, float* __restrict__ bqkv) {
  int t = blockIdx.x * 256 + threadIdx.x;
  if (t < 3072)
    bqkv[t] = (t < 1024) ? bQ[t] : (t < 2048) ? bK[t - 1024] : bV[t - 2048];
}

// ---------------- layernorm (ln_pre): f32 in -> bf16 out ----------------
__global__ void ln_f32(const float* __restrict__ x, u16* __restrict__ y) {
  __shared__ float red1[4];
  __shared__ float red2[4];
  int token = blockIdx.x;
  int tid = threadIdx.x;
  int w = tid >> 6;
  const float* xr = x + (size_t)token * 1024;
  float4v v = *(const float4v*)(xr + tid * 4);
  float s = v[0] + v[1] + v[2] + v[3];
#pragma unroll
  for (int m = 32; m >= 1; m >>= 1) s += __shfl_xor(s, m);
  if ((tid & 63) == 0) red1[w] = s;
  __syncthreads();
  float mean = (red1[0] + red1[1] + red1[2] + red1[3]) * (1.0f / 1024.0f);
  float ss = 0.0f;
#pragma unroll
  for (int j = 0; j < 4; ++j) { v[j] -= mean; ss += v[j] * v[j]; }
#pragma unroll
  for (int m = 32; m >= 1; m >>= 1) ss += __shfl_xor(ss, m);
  if ((tid & 63) == 0) red2[w] = ss;
  __syncthreads();
  float ms = (red2[0] + red2[1] + red2[2] + red2[3]) * (1.0f / 1024.0f);
  float inv = 1.0f / sqrtf(ms + 1e-5f);
  ushort4v o;
#pragma unroll
  for (int j = 0; j < 4; ++j) o[j] = f2bf(v[j] * inv);
  *(ushort4v*)(y + (size_t)token * 1024 + tid * 4) = o;
}

// ---------------- GEMM: C[M,N] = A[M,K](bf16, stride lda) * Bw[N,K]^T ----------------
// (128x BN tile, 2-barrier structure; swizzled LDS; optional prefetch dbuf)
template <int BN, int BK, bool GELU, bool VSPLIT, bool DBUF, typename TO, typename TR>
__global__ __launch_bounds__(256) void gemm_bt(
    const u16* __restrict__ A, const u16* __restrict__ Bw,
    const float* __restrict__ bias, const TR* __restrict__ resid,
    TO* __restrict__ C, u16* __restrict__ vTout, int M, int N, int K,
    int lda, int ldc) {
  constexpr int BM = 128;
  constexpr int SEGS = BK / 8;           // 16B chunks per tile row
  constexpr int SMASK = SEGS - 1;
  constexpr int FI = 4, FJ = BN / 32;
  constexpr int CA = BM * SEGS / 256;    // chunks per thread (A tile)
  constexpr int CB = BN * SEGS / 256;
  constexpr int NB = DBUF ? 2 : 1;
  __shared__ __align__(16) u16 As[NB][BM * BK];
  __shared__ __align__(16) u16 Bs[NB][BN * BK];
  const int tid = threadIdx.x;
  const int w = tid >> 6, lane = tid & 63;
  const int quad = lane >> 4, l16 = lane & 15;
  const int m0 = blockIdx.x * BM, n0 = blockIdx.y * BN;
  const int wm = (w >> 1) * 64, wn = (w & 1) * (BN / 2);
  const int rmask = l16 & SMASK;  // == row & SMASK for all fragment rows
  float4v acc[FI][FJ] = {};

  auto stage = [&](int buf, int k0) {
#pragma unroll
    for (int t = 0; t < CA; ++t) {
      int chunk = (w * CA + t) * 64 + lane;
      int row = chunk / SEGS, seg = chunk % SEGS;
      int sseg = seg ^ (row & SMASK);
      gload_lds16(A + (size_t)(m0 + row) * lda + k0 + sseg * 8,
                  As[buf] + (w * CA + t) * 512);
    }
#pragma unroll
    for (int t = 0; t < CB; ++t) {
      int chunk = (w * CB + t) * 64 + lane;
      int row = chunk / SEGS, seg = chunk % SEGS;
      int sseg = seg ^ (row & SMASK);
      gload_lds16(Bw + (size_t)(n0 + row) * K + k0 + sseg * 8,
                  Bs[buf] + (w * CB + t) * 512);
    }
  };
  auto compute = [&](int buf) {
#pragma unroll
    for (int kk = 0; kk < BK; kk += 32) {
      short8 a[FI], b[FJ];
#pragma unroll
      for (int fi = 0; fi < FI; ++fi)
        a[fi] = *(const short8*)(As[buf] + (wm + fi * 16 + l16) * BK +
                                 ((((kk >> 3) + quad) ^ rmask) << 3));
#pragma unroll
      for (int fj = 0; fj < FJ; ++fj)
        b[fj] = *(const short8*)(Bs[buf] + (wn + fj * 16 + l16) * BK +
                                 ((((kk >> 3) + quad) ^ rmask) << 3));
#pragma unroll
      for (int fi = 0; fi < FI; ++fi)
#pragma unroll
        for (int fj = 0; fj < FJ; ++fj)
          acc[fi][fj] = __builtin_amdgcn_mfma_f32_16x16x32_bf16(
              a[fi], b[fj], acc[fi][fj], 0, 0, 0);
    }
  };

  if constexpr (DBUF) {
    stage(0, 0);
    __syncthreads();  // drain prologue loads
    int cur = 0;
    for (int k0 = 0; k0 < K; k0 += BK) {
      if (k0 + BK < K) stage(cur ^ 1, k0 + BK);  // prefetch next tile
      compute(cur);                               // overlaps with loads in flight
      __syncthreads();  // drain prefetch + guard buf reuse
      cur ^= 1;
    }
  } else {
    for (int k0 = 0; k0 < K; k0 += BK) {
      __syncthreads();
      stage(0, k0);
      __syncthreads();
      compute(0);
    }
  }

#pragma unroll
  for (int fi = 0; fi < FI; ++fi) {
#pragma unroll
    for (int fj = 0; fj < FJ; ++fj) {
      int col = n0 + wn + fj * 16 + l16;
      float bv = bias ? bias[col] : 0.0f;
#pragma unroll
      for (int r = 0; r < 4; ++r) {
        int row = m0 + wm + fi * 16 + quad * 4 + r;
        float val = acc[fi][fj][r] + bv;
        if (resid) val += ldres(resid + (size_t)row * N + col);
        if (GELU) val = gelu_new(val);
        if (VSPLIT && col < 1024) val *= 0.18033688011112042f;  // Q pre-scale
        if (VSPLIT && col >= 2048) {
          vTout[(size_t)(col - 2048) * 4096 + row] = f2bf(val);
        } else if constexpr (sizeof(TO) == 2) {
          C[(size_t)row * ldc + col] = f2bf(val);
        } else {
          C[(size_t)row * ldc + col] = val;
        }
      }
    }
  }
}

// ---------------- 256x256 GEMM, counted-vmcnt 2-deep pipeline (T3/T4) ----------------
// C[M,N](bf16) = gelu(A[M,K]*Bw[N,K]^T + bias). 512 threads = 8 waves (2Mx4N),
// per-wave 128x64 output. LDS 128KB: 2 bufs x (256x64 A + 256x64 B).
// Pipeline: while computing tile t from buf[cur], tile t+1 is landing in
// buf[cur^1] (issued last iter) and tile t+2 is issued into buf[cur] right
// after the release barrier. s_waitcnt vmcnt(8) (= one stage in flight)
// replaces the vmcnt(0) drain -- loads stay in flight across barriers.
// Same both-sides XOR seg-swizzle as gemm_bt (measured 0 bank conflicts).
// XCD-chunked block mapping: each XCD owns a 4m x 8n chunk (A 2MB + B 4MB ~ L2).
template <bool GELU>
__global__ __launch_bounds__(512, 2) void gemm256(
    const u16* __restrict__ A, const u16* __restrict__ Bw,
    const float* __restrict__ bias, u16* __restrict__ C,
    int M, int N, int K, int lda, int ldc) {
  constexpr int BK = 64;
  __shared__ __align__(16) u16 As[2][256 * BK];
  __shared__ __align__(16) u16 Bs[2][256 * BK];
  const int tid = threadIdx.x;
  const int w = tid >> 6, lane = tid & 63;
  const int quad = lane >> 4, l16 = lane & 15;
  const int rmask = l16 & 7;
  // XCD-chunked mapping: id%8 = XCD; XCDs tile 4x2 over (m,n); 32 locals = 4m x 8n
  const int id = blockIdx.x;
  const int xcd = id & 7, local = id >> 3;
  const int mt = (xcd & 3) * 4 + (local >> 3);
  const int ntile = (xcd >> 2) * 8 + (local & 7);
  const int m0 = mt * 256, n0 = ntile * 256;
  const int wm = (w >> 2) * 128, wn = (w & 3) * 64;

  // per-thread staging sources: 4 A-chunks + 4 B-chunks, 16B each, per K-tile.
  // chunk c = (w*4+t)*64 + lane; row = c>>3; seg = c&7; source seg = seg^(row&7)
  const u16* ag[4];
  const u16* bg[4];
#pragma unroll
  for (int t = 0; t < 4; ++t) {
    int chunk = (w * 4 + t) * 64 + lane;
    int row = chunk >> 3, seg = chunk & 7;
    int sseg = seg ^ (row & 7);
    ag[t] = A + (size_t)(m0 + row) * lda + sseg * 8;
    bg[t] = Bw + (size_t)(n0 + row) * K + sseg * 8;
  }

  float4v acc[8][4] = {};

  auto stage = [&](int buf, int k0) {
#pragma unroll
    for (int t = 0; t < 4; ++t)
      gload_lds16(ag[t] + k0, &As[buf][(w * 4 + t) * 512]);
#pragma unroll
    for (int t = 0; t < 4; ++t)
      gload_lds16(bg[t] + k0, &Bs[buf][(w * 4 + t) * 512]);
  };
  auto compute = [&](int buf) {
    const u16* Ab = &As[buf][0];
    const u16* Bb = &Bs[buf][0];
    short8 bfrag[4][2];
#pragma unroll
    for (int ni = 0; ni < 4; ++ni)
#pragma unroll
      for (int k2 = 0; k2 < 2; ++k2)
        bfrag[ni][k2] = *(const short8*)(Bb + (wn + ni * 16 + l16) * BK +
                                         (((k2 * 4 + quad) ^ rmask) << 3));
#pragma unroll
    for (int mi = 0; mi < 8; ++mi) {
      short8 afrag[2];
#pragma unroll
      for (int k2 = 0; k2 < 2; ++k2)
        afrag[k2] = *(const short8*)(Ab + (wm + mi * 16 + l16) * BK +
                                     (((k2 * 4 + quad) ^ rmask) << 3));
#pragma unroll
      for (int ni = 0; ni < 4; ++ni)
#pragma unroll
        for (int k2 = 0; k2 < 2; ++k2)
          acc[mi][ni] = __builtin_amdgcn_mfma_f32_16x16x32_bf16(
              afrag[k2], bfrag[ni][k2], acc[mi][ni], 0, 0, 0);
    }
  };

  const int ntk = K / BK;
  // prologue: stage tiles 0 and 1; wait for tile 0 (8 of 16 loads retired)
  stage(0, 0);
  stage(1, BK);
  asm volatile("s_waitcnt vmcnt(8)" ::: "memory");
  asm volatile("s_barrier" ::: "memory");
  int cur = 0;
  for (int t = 0; t < ntk; ++t) {
    compute(cur);
    // release buf[cur]: all waves' LDS reads complete
    asm volatile("s_waitcnt lgkmcnt(0)" ::: "memory");
    asm volatile("s_barrier" ::: "memory");
    if (t + 2 < ntk) {
      stage(cur, (t + 2) * BK);                     // t+2 into freed buffer
      asm volatile("s_waitcnt vmcnt(8)" ::: "memory");  // t+1 fully landed
    } else {
      asm volatile("s_waitcnt vmcnt(0)" ::: "memory");  // drain tail
    }
    asm volatile("s_barrier" ::: "memory");  // publish t+1 to all waves
    cur ^= 1;
  }

#pragma unroll
  for (int mi = 0; mi < 8; ++mi) {
#pragma unroll
    for (int ni = 0; ni < 4; ++ni) {
      int col = n0 + wn + ni * 16 + l16;
      float bv = bias[col];
#pragma unroll
      for (int r = 0; r < 4; ++r) {
        int row = m0 + wm + mi * 16 + quad * 4 + r;
        float val = acc[mi][ni][r] + bv;
        if (GELU) val = gelu_new(val);
        C[(size_t)row * ldc + col] = f2bf(val);
      }
    }
  }
}

// ---------------- single-pass flash attention (causal, online softmax, exp2) ----------------
__global__ __launch_bounds__(256) void attn_flash(u16* __restrict__ qk,
                                                  const u16* __restrict__ vT) {
  constexpr int PADK = 72;
  constexpr float THR2 = 10.0f;  // defer-max threshold, log2 domain (P <= 2^10)
  __shared__ __align__(16) u16 Ks[64 * PADK];
  __shared__ __align__(16) u16 Vt[64 * PADK];
  __shared__ __align__(16) u16 Ps[4][16 * PADK];
  const int id = blockIdx.x;
  const int qt = 31 - (id >> 5);  // longest blocks first
  const int combo = id & 31;
  const int head = combo >> 1, b = combo & 1;
  const int tid = threadIdx.x;
  const int w = tid >> 6, lane = tid & 63;
  const int quad = lane >> 4, l16 = lane & 15;
  const int q0 = qt * 64;
  const size_t tokB = (size_t)b * 2048;

  short8 aq[2];
#pragma unroll
  for (int ks = 0; ks < 2; ++ks)
    aq[ks] = *(const short8*)(qk + (tokB + q0 + w * 16 + l16) * 2048 +
                              head * 64 + ks * 32 + quad * 8);

  const u16* kbase = qk + tokB * 2048 + 1024 + head * 64;   // + (kk0+row)*2048 + seg*8
  const u16* vbase = vT + (size_t)head * 64 * 4096 + tokB;  // + row*4096 + kk0 + seg*8

  // ones-column B-fragment: col 0 of a 16-col tile = 1.0, rest 0.
  short8 bones = {};
  if (l16 == 0) {
#pragma unroll
    for (int j = 0; j < 8; ++j) bones[j] = (short)0x3F80;
  }

  float m_st[4] = {-1e30f, -1e30f, -1e30f, -1e30f};
  float4v o_acc[4] = {};
  float4v o5 = {0.f, 0.f, 0.f, 0.f};  // row-sums (col 0 lanes only)

  // staging geometry: each thread owns 2 consecutive 16B segs of one row
  const int srow = tid >> 2;
  const int sseg = (tid & 3) * 2;
  const u16* kptr = kbase + (size_t)srow * 2048 + sseg * 8;
  const u16* vptr = vbase + (size_t)srow * 4096 + sseg * 8;
  u16* ksl = Ks + srow * PADK + sseg * 8;
  u16* vsl = Vt + srow * PADK + sseg * 8;

  // prologue: prefetch tile 0 into regs
  short8 pk0 = *(const short8*)(kptr);
  short8 pk1 = *(const short8*)(kptr + 8);
  short8 pv0 = *(const short8*)(vptr);
  short8 pv1 = *(const short8*)(vptr + 8);

  for (int kt = 0; kt <= qt; ++kt) {
    const int kk0 = kt * 64;
    __syncthreads();  // previous compute done reading Ks/Vt
    *(short8*)(ksl) = pk0;
    *(short8*)(ksl + 8) = pk1;
    *(short8*)(vsl) = pv0;
    *(short8*)(vsl + 8) = pv1;
    __syncthreads();  // LDS writes visible
    if (kt < qt) {    // T14: issue next-tile loads; they fly during compute
      const u16* kp = kptr + (size_t)(kk0 + 64) * 2048;
      const u16* vp = vptr + kk0 + 64;
      pk0 = *(const short8*)(kp);
      pk1 = *(const short8*)(kp + 8);
      pv0 = *(const short8*)(vp);
      pv1 = *(const short8*)(vp + 8);
    }

    float4v s[4];
    __builtin_amdgcn_s_setprio(1);
#pragma unroll
    for (int fj = 0; fj < 4; ++fj) {
      float4v t = {0.f, 0.f, 0.f, 0.f};
#pragma unroll
      for (int ks = 0; ks < 2; ++ks) {
        short8 bk = *(const short8*)(Ks + (fj * 16 + l16) * PADK + ks * 32 + quad * 8);
        t = __builtin_amdgcn_mfma_f32_16x16x32_bf16(aq[ks], bk, t, 0, 0, 0);
      }
      s[fj] = t;
    }
    __builtin_amdgcn_s_setprio(0);
    if (kt == qt) {
#pragma unroll
      for (int fj = 0; fj < 4; ++fj) {
        int col = kk0 + fj * 16 + l16;
#pragma unroll
        for (int r = 0; r < 4; ++r) {
          int row = q0 + w * 16 + quad * 4 + r;
          if (col > row) s[fj][r] = -1e30f;
        }
      }
    }
    float mx[4];
#pragma unroll
    for (int r = 0; r < 4; ++r) {
      float m = fmaxf(fmaxf(s[0][r], s[1][r]), fmaxf(s[2][r], s[3][r]));
      m = fmaxf(m, __shfl_xor(m, 1));
      m = fmaxf(m, __shfl_xor(m, 2));
      m = fmaxf(m, __shfl_xor(m, 4));
      m = fmaxf(m, __shfl_xor(m, 8));
      mx[r] = m;
    }
    // defer-max: only rescale when the max grew by more than THR2
    bool need = false;
#pragma unroll
    for (int r = 0; r < 4; ++r) need |= (mx[r] > m_st[r] + THR2);
    if (__any(need)) {
#pragma unroll
      for (int r = 0; r < 4; ++r) {
        float mnew = fmaxf(m_st[r], mx[r]);
        float al = __builtin_amdgcn_exp2f(m_st[r] - mnew);
        m_st[r] = mnew;
        o5[r] *= al;
#pragma unroll
        for (int fj = 0; fj < 4; ++fj) o_acc[fj][r] *= al;
      }
    }
    // P = exp2(s - m), packed bf16 convert, store to Ps
#pragma unroll
    for (int fj = 0; fj < 4; ++fj) {
#pragma unroll
      for (int r = 0; r < 4; r += 2) {
        float e0 = __builtin_amdgcn_exp2f(s[fj][r] - m_st[r]);
        float e1 = __builtin_amdgcn_exp2f(s[fj][r + 1] - m_st[r + 1]);
        unsigned int pp = cvt_pk_bf16(e0, e1);
        Ps[w][(quad * 4 + r) * PADK + fj * 16 + l16] = (u16)pp;
        Ps[w][(quad * 4 + r + 1) * PADK + fj * 16 + l16] = (u16)(pp >> 16);
      }
    }
    short8 ap[2];
#pragma unroll
    for (int ks = 0; ks < 2; ++ks)
      ap[ks] = *(const short8*)(&Ps[w][l16 * PADK + ks * 32 + quad * 8]);
    __builtin_amdgcn_s_setprio(1);
#pragma unroll
    for (int fj = 0; fj < 4; ++fj)
#pragma unroll
      for (int ks = 0; ks < 2; ++ks) {
        short8 bv = *(const short8*)(Vt + (fj * 16 + l16) * PADK + ks * 32 + quad * 8);
        o_acc[fj] = __builtin_amdgcn_mfma_f32_16x16x32_bf16(ap[ks], bv, o_acc[fj], 0, 0, 0);
      }
#pragma unroll
    for (int ks = 0; ks < 2; ++ks)
      o5 = __builtin_amdgcn_mfma_f32_16x16x32_bf16(ap[ks], bones, o5, 0, 0, 0);
    __builtin_amdgcn_s_setprio(0);
  }
#pragma unroll
  for (int r = 0; r < 4; ++r) {
    float lsum = __shfl(o5[r], lane & 48);  // broadcast col-0 lane of the quad
    float inv = 1.0f / lsum;
    int row = q0 + w * 16 + quad * 4 + r;
#pragma unroll
    for (int fj = 0; fj < 4; ++fj)
      qk[(tokB + row) * 2048 + head * 64 + fj * 16 + l16] =
          f2bf(o_acc[fj][r] * inv);
  }
}

// ---------------- launcher ----------------
extern "C" void kernel_launch(void* const* d_in, const int* in_sizes, int n_in,
                              void* d_out, int out_size, void* d_ws, size_t ws_size,
                              hipStream_t stream) {
  const float* x = (const float*)d_in[0];
  const float* W_Q = (const float*)d_in[1];
  const float* W_K = (const float*)d_in[2];
  const float* W_V = (const float*)d_in[3];
  const float* W_O = (const float*)d_in[4];
  const float* b_Q = (const float*)d_in[5];
  const float* b_K = (const float*)d_in[6];
  const float* b_V = (const float*)d_in[7];
  const float* b_O = (const float*)d_in[8];
  const float* W_in = (const float*)d_in[9];
  const float* b_in = (const float*)d_in[10];
  const float* W_out = (const float*)d_in[11];
  const float* b_out = (const float*)d_in[12];
  float* out = (float*)d_out;

  char* ws = (char*)d_ws;
  u16* Wqkv = (u16*)(ws);                 // [0, 6291456)
  u16* Wot  = (u16*)(ws + 6291456);       // [6291456, 8388608)
  u16* Wib  = (u16*)(ws + 8388608);       // [8388608, 16777216)
  u16* Wob  = (u16*)(ws + 16777216);      // [16777216, 25165824)
  float* bqkv = (float*)(ws + 25165824);  // [25165824, 25178112)
  u16* xn   = (u16*)(ws + 25178112);      // [25178112, 33566720)
  u16* qk   = (u16*)(ws + 33566720);      // [33566720, 50343936)  4096*2048 bf16
  u16* vT   = (u16*)(ws + 50343936);      // [50343936, 58732544)  1024*4096 bf16
  u16* hbuf = (u16*)(ws + 33566720);      // overlays qk+vT, 4096*4096, ends 67121152
  float* rm = (float*)(ws + 67121152);    // [67121152, 83898368)

  cvt_bf16_multi<<<5632, 256, 0, stream>>>(W_Q, W_K, W_V, W_in, W_out,
                                           Wqkv, Wqkv + 1048576, Wqkv + 2097152,
                                           Wib, Wob);
  prep_wo<<<512, 256, 0, stream>>>(W_O, Wot);
  prep_bqkv<<<12, 256, 0, stream>>>(b_Q, b_K, b_V, bqkv);

  ln_f32<<<4096, 256, 0, stream>>>(x, xn);
  // QKV: Q,K -> qk[4096][2048] (Q pre-scaled); V -> vT[1024][4096]
  gemm_bt<128, 64, false, true, false, u16, float><<<dim3(32, 24), 256, 0, stream>>>(
      xn, Wqkv, bqkv, (const float*)nullptr, qk, vT, 4096, 3072, 1024, 1024, 2048);
  attn_flash<<<1024, 256, 0, stream>>>(qk, vT);
  // attn-out: BN=64/BK=64 + swizzle + prefetch dbuf (512 blocks = 2/CU).
  gemm_bt<64, 64, false, false, true, float, float><<<dim3(32, 16), 256, 0, stream>>>(
      qk /*z in q half, lda=2048*/, Wot, b_O, x, rm, nullptr, 4096, 1024, 1024, 2048, 1024);
  ln_f32<<<4096, 256, 0, stream>>>(rm, xn);
  // MLP-in: 256x256 counted-vmcnt pipeline (256 blocks = 1/CU, 8 waves).
  gemm256<true><<<256, 512, 0, stream>>>(xn, Wib, b_in, hbuf,
                                         4096, 4096, 1024, 1024, 4096);
  // MLP-out: BN=64/BK=64 + swizzle + prefetch dbuf (512 blocks = 2/CU).
  gemm_bt<64, 64, false, false, true, float, float><<<dim3(32, 16), 256, 0, stream>>>(
      hbuf, Wob, b_out, rm, out, nullptr, 4096, 1024, 4096, 4096, 1024);
}